// Round 9
// baseline (536.328 us; speedup 1.0000x reference)
//
#include <hip/hip_runtime.h>
#include <hip/hip_bf16.h>

#define D      128
#define NHEAD  8
#define FE     5
#define LSEQ   4096
#define EPB    64          // edges per block in edge_kernel
#define NNODE  16384
#define EPS_LN 1e-5f
#define EPS_SM 1e-16f

typedef unsigned short ushort_t;
typedef __bf16 bf16x8 __attribute__((ext_vector_type(8)));
typedef float  f32x4  __attribute__((ext_vector_type(4)));

__device__ __forceinline__ ushort_t f2bf(float x) {
    __hip_bfloat16 b = __float2bfloat16(x);
    return __builtin_bit_cast(unsigned short, b);
}
__device__ __forceinline__ float bf2f(ushort_t u) {
    __hip_bfloat16 b = __builtin_bit_cast(__hip_bfloat16, u);
    return __bfloat162float(b);
}
__device__ __forceinline__ float i2f(int x)  { return __builtin_bit_cast(float, x); }
__device__ __forceinline__ int   f2i(float x){ return __builtin_bit_cast(int, x); }

union Pk8 { ushort_t u[8]; uint4 v; };

// ---------------------------------------------------------------------------
// setup_kernel: independent jobs partitioned by blockIdx
//   [0, 3*nqb)        : qkv GEMMs, 32 rows/block, bf16 output
//   [3*nqb, +17)      : w2 swizzle into MFMA B-fragment layout
//   [3*nqb+17, +1024) : head histogram (cnt pre-zeroed by memset)
// NOTE: no in-kernel scan/fence — 1024 device-scope fences cost ~100 µs (R7).
// ---------------------------------------------------------------------------
__global__ __launch_bounds__(256) void setup_kernel(
    const float* __restrict__ key, const float* __restrict__ value,
    const float* __restrict__ query,
    const float* __restrict__ key_w, const float* __restrict__ key_b,
    const float* __restrict__ value_w, const float* __restrict__ value_b,
    const float* __restrict__ query_w, const float* __restrict__ query_b,
    ushort_t* __restrict__ k16, ushort_t* __restrict__ v16, ushort_t* __restrict__ q16,
    const float* __restrict__ ekw2, const float* __restrict__ evw2,
    const float* __restrict__ eaw2,
    ushort_t* __restrict__ eksw, ushort_t* __restrict__ evsw, ushort_t* __restrict__ easw,
    const int* __restrict__ bidx, const int* __restrict__ hidx,
    int* __restrict__ cnt, int nqb, int E)
{
    const int t  = threadIdx.x;
    const int nq = 3 * nqb;

    if ((int)blockIdx.x < nq) {
        // ---------------- qkv GEMM: [Nx128]@[128x128], 32 rows/block --------
        __shared__ float xs[2][D][20];
        const int which = blockIdx.x / nqb;
        const int r0    = (blockIdx.x % nqb) * 32;
        const float* X = (which == 0) ? key   : (which == 1) ? value   : query;
        const float* W = (which == 0) ? key_w : (which == 1) ? value_w : query_w;
        const float* bias = (which == 0) ? key_b : (which == 1) ? value_b : query_b;
        ushort_t* Y = (which == 0) ? k16 : (which == 1) ? v16 : q16;

        const int rg = t >> 7, j = t & 127;
        const int rbase = r0 + rg * 16;
        {
            float tmp[16];
            #pragma unroll
            for (int r = 0; r < 16; ++r) tmp[r] = X[(size_t)(rbase + r) * D + j];
            #pragma unroll
            for (int c = 0; c < 4; ++c)
                *(float4*)&xs[rg][j][c * 4] = float4{tmp[c*4], tmp[c*4+1], tmp[c*4+2], tmp[c*4+3]};
        }
        __syncthreads();
        float acc[16];
        const float b = bias[j];
        #pragma unroll
        for (int r = 0; r < 16; ++r) acc[r] = b;
        #pragma unroll 4
        for (int i = 0; i < D; ++i) {
            const float w = W[i * D + j];
            #pragma unroll
            for (int c = 0; c < 4; ++c) {
                const float4 x4 = *(const float4*)&xs[rg][i][c * 4];
                acc[c*4+0] = fmaf(x4.x, w, acc[c*4+0]);
                acc[c*4+1] = fmaf(x4.y, w, acc[c*4+1]);
                acc[c*4+2] = fmaf(x4.z, w, acc[c*4+2]);
                acc[c*4+3] = fmaf(x4.w, w, acc[c*4+3]);
            }
        }
        #pragma unroll
        for (int r = 0; r < 16; ++r) Y[(size_t)(rbase + r) * D + j] = f2bf(acc[r]);
        return;
    }

    const int b2 = blockIdx.x - nq;
    if (b2 < 17) {
        // ---------------- w2 swizzle --------------------------------------
        const int g = b2 * 256 + t;
        const float* src; ushort_t* dst; int frag, ncols, nvalid;
        if (g < 2048)      { src = ekw2; dst = eksw; frag = g;        ncols = 128; nvalid = 128; }
        else if (g < 4096) { src = evw2; dst = evsw; frag = g - 2048; ncols = 128; nvalid = 128; }
        else if (g < 4352) { src = eaw2; dst = easw; frag = g - 4096; ncols = 8;   nvalid = 8; }
        else return;
        const int s = (frag >> 6) & 3;
        const int l = frag & 63;
        const int n = ((frag >> 8) << 4) + (l & 15);
        Pk8 pk;
        #pragma unroll
        for (int j = 0; j < 8; ++j) {
            const int k = s * 32 + (l >> 4) * 8 + j;
            const float v = (n < nvalid) ? src[k * ncols + n] : 0.f;
            pk.u[j] = f2bf(v);
        }
        *(uint4*)(dst + (size_t)frag * 8) = pk.v;
        return;
    }

    // ---------------- histogram ------------------------------------------
    const int e = (b2 - 17) * 256 + t;
    if (e < E) atomicAdd(&cnt[bidx[e] * LSEQ + hidx[e]], 1);
}

// ---------------------------------------------------------------------------
// Exclusive scan of the 16384-bin histogram (single block, ~5 µs).
// ---------------------------------------------------------------------------
__global__ __launch_bounds__(1024) void scan16k(
    const int* __restrict__ cnt, int* __restrict__ base)
{
    __shared__ int part[1024];
    const int t = threadIdx.x;
    int v[16], ex[16], s = 0;
    #pragma unroll
    for (int i = 0; i < 16; ++i) v[i] = cnt[t * 16 + i];
    #pragma unroll
    for (int i = 0; i < 16; ++i) { ex[i] = s; s += v[i]; }
    part[t] = s;
    __syncthreads();
    for (int off = 1; off < 1024; off <<= 1) {
        const int x = (t >= off) ? part[t - off] : 0;
        __syncthreads();
        part[t] += x;
        __syncthreads();
    }
    const int boff = (t > 0) ? part[t - 1] : 0;
    #pragma unroll
    for (int i = 0; i < 16; ++i) base[t * 16 + i] = boff + ex[i];
    if (t == 1023) base[NNODE] = boff + s;
}

// ---------------------------------------------------------------------------
// scatter_rec: assign each edge its sorted slot p and write a packed 32 B
// record rec[p] = {ef[5], head_node, tail_node, pad}. Edge kernel then
// reads rec[] fully coalesced despite the permutation.
// ---------------------------------------------------------------------------
__global__ __launch_bounds__(256) void scatter_rec(
    const int* __restrict__ bidx, const int* __restrict__ hidx, const int* __restrict__ tidx,
    const float* __restrict__ edge_feats,
    const int* __restrict__ base, int* __restrict__ cnt,
    float* __restrict__ rec, int E)
{
    const int e = blockIdx.x * 256 + threadIdx.x;
    if (e >= E) return;
    const int bb = bidx[e];
    const int nh = bb * LSEQ + hidx[e];
    const int nt = bb * LSEQ + tidx[e];
    const int slot = atomicSub(&cnt[nh], 1) - 1;
    const int p = base[nh] + slot;
    float ef[FE];
    #pragma unroll
    for (int f = 0; f < FE; ++f) ef[f] = edge_feats[(size_t)e * FE + f];
    *(float4*)&rec[(size_t)p * 8]     = float4{ef[0], ef[1], ef[2], ef[3]};
    *(float4*)&rec[(size_t)p * 8 + 4] = float4{ef[4], i2f(nh), i2f(nt), 0.f};
}

// ---------------------------------------------------------------------------
// Fused edge kernel — barrier-free wave-local pipeline over SORTED positions.
// Block b handles p in [b*64, b*64+64); all edge data from rec[] (coalesced).
// Writes ex (f32 [p][8]) and vs (bf16 [p][128]) at sorted positions.
// __launch_bounds__(256,8): VGPR fits 64 under (256,4) already; 8 blocks/CU
// (LDS 15.4K x 8 = 123K < 160K) doubles latency-hiding for the kqv gathers.
// ---------------------------------------------------------------------------
__global__ __launch_bounds__(256, 8) void edge_kernel(
    const float* __restrict__ rec,
    const float* __restrict__ ea_w1, const float* __restrict__ ea_b1,
    const float* __restrict__ ea_g,  const float* __restrict__ ea_be, const float* __restrict__ ea_b2,
    const float* __restrict__ ek_w1, const float* __restrict__ ek_b1,
    const float* __restrict__ ek_g,  const float* __restrict__ ek_be, const float* __restrict__ ek_b2,
    const float* __restrict__ ev_w1, const float* __restrict__ ev_b1,
    const float* __restrict__ ev_g,  const float* __restrict__ ev_be, const float* __restrict__ ev_b2,
    const ushort_t* __restrict__ easw, const ushort_t* __restrict__ eksw, const ushort_t* __restrict__ evsw,
    const ushort_t* __restrict__ k16, const ushort_t* __restrict__ q16, const ushort_t* __restrict__ v16,
    float* __restrict__ ex_ws, ushort_t* __restrict__ vs_ws)
{
    __shared__ float pw1[3][FE * D];
    __shared__ float pb1[3][D], pg[3][D], pbe[3][D];
    __shared__ float pb2k[D], pb2v[D], pb2a[NHEAD];
    __shared__ float ef_s[EPB][FE];
    __shared__ int   eh_s[EPB], et_s[EPB];

    const int t   = threadIdx.x;
    const int e0g = blockIdx.x * EPB;   // sorted-position base

    for (int i = t; i < FE * D; i += 256) { pw1[0][i] = ea_w1[i]; pw1[1][i] = ek_w1[i]; pw1[2][i] = ev_w1[i]; }
    if (t < D) {
        pb1[0][t] = ea_b1[t]; pb1[1][t] = ek_b1[t]; pb1[2][t] = ev_b1[t];
        pg [0][t] = ea_g [t]; pg [1][t] = ek_g [t]; pg [2][t] = ev_g [t];
        pbe[0][t] = ea_be[t]; pbe[1][t] = ek_be[t]; pbe[2][t] = ev_be[t];
        pb2k[t] = ek_b2[t];   pb2v[t] = ev_b2[t];
        if (t < NHEAD) pb2a[t] = ea_b2[t];
    }
    if (t < 128) {
        const int pl = t >> 1, half = t & 1;
        const float4 v = *(const float4*)&rec[((size_t)e0g + pl) * 8 + half * 4];
        if (half == 0) {
            ef_s[pl][0] = v.x; ef_s[pl][1] = v.y; ef_s[pl][2] = v.z; ef_s[pl][3] = v.w;
        } else {
            ef_s[pl][4] = v.x; eh_s[pl] = f2i(v.y); et_s[pl] = f2i(v.z);
        }
    }
    __syncthreads();     // the only barrier

    const int mt   = t >> 6;        // wave id == m-tile
    const int l    = t & 63;        // lane
    const int qt   = l & 3;         // producer: dim-chunk quarter
    const int per  = l >> 2;        // producer: edge row 0..15
    const int row0 = (l >> 4) * 4;  // consumer: accumulator row base
    const int colb = l & 15;        // consumer: column within n-tile
    const int src  = 4 * colb + (l >> 4);   // shfl source for A-frag chunks
    const int bsrc = (l & 48);      // row-group base for ea broadcasts

    int tn[4], hnn[4];
    #pragma unroll
    for (int r = 0; r < 4; ++r) { tn[r] = et_s[mt*16 + row0 + r]; hnn[r] = eh_s[mt*16 + row0 + r]; }

    float efr[FE];
    #pragma unroll
    for (int f = 0; f < FE; ++f) efr[f] = ef_s[mt*16 + per][f];

    auto first_layer = [&](int m, uint4 pk[4]) {
        const float4* w1v = (const float4*)&pw1[m][0];
        const float4* b1v = (const float4*)&pb1[m][0];
        const float4* gv  = (const float4*)&pg[m][0];
        const float4* bev = (const float4*)&pbe[m][0];
        float4 hv[4][2];
        float s1 = 0.f, s2 = 0.f;
        #pragma unroll
        for (int s = 0; s < 4; ++s) {
            #pragma unroll
            for (int hc = 0; hc < 2; ++hc) {
                const int idx = s * 8 + qt * 2 + hc;
                float4 a = b1v[idx];
                #pragma unroll
                for (int f = 0; f < FE; ++f) {
                    const float sc = efr[f];
                    const float4 w = w1v[f * 32 + idx];
                    a.x = fmaf(sc, w.x, a.x); a.y = fmaf(sc, w.y, a.y);
                    a.z = fmaf(sc, w.z, a.z); a.w = fmaf(sc, w.w, a.w);
                }
                a.x = fmaxf(a.x, 0.f); a.y = fmaxf(a.y, 0.f);
                a.z = fmaxf(a.z, 0.f); a.w = fmaxf(a.w, 0.f);
                hv[s][hc] = a;
                s1 += a.x + a.y + a.z + a.w;
                s2 += a.x*a.x + a.y*a.y + a.z*a.z + a.w*a.w;
            }
        }
        s1 += __shfl_xor(s1, 1); s1 += __shfl_xor(s1, 2);
        s2 += __shfl_xor(s2, 1); s2 += __shfl_xor(s2, 2);
        const float mu = s1 * (1.f / 128.f);
        const float rs = rsqrtf(s2 * (1.f / 128.f) - mu * mu + EPS_LN);
        #pragma unroll
        for (int s = 0; s < 4; ++s) {
            const int idx = s * 8 + qt * 2;
            const float4 x0 = hv[s][0], x1 = hv[s][1];
            const float4 g0 = gv[idx], g1 = gv[idx + 1];
            const float4 b0 = bev[idx], b1 = bev[idx + 1];
            Pk8 p8;
            p8.u[0] = f2bf(fmaf((x0.x - mu) * rs, g0.x, b0.x));
            p8.u[1] = f2bf(fmaf((x0.y - mu) * rs, g0.y, b0.y));
            p8.u[2] = f2bf(fmaf((x0.z - mu) * rs, g0.z, b0.z));
            p8.u[3] = f2bf(fmaf((x0.w - mu) * rs, g0.w, b0.w));
            p8.u[4] = f2bf(fmaf((x1.x - mu) * rs, g1.x, b1.x));
            p8.u[5] = f2bf(fmaf((x1.y - mu) * rs, g1.y, b1.y));
            p8.u[6] = f2bf(fmaf((x1.z - mu) * rs, g1.z, b1.z));
            p8.u[7] = f2bf(fmaf((x1.w - mu) * rs, g1.w, b1.w));
            pk[s] = p8.v;
        }
    };

    auto gather_afr = [&](const uint4 pk[4], bf16x8 afr[4]) {
        #pragma unroll
        for (int s = 0; s < 4; ++s) {
            uint4 w;
            w.x = (unsigned)__shfl((int)pk[s].x, src);
            w.y = (unsigned)__shfl((int)pk[s].y, src);
            w.z = (unsigned)__shfl((int)pk[s].z, src);
            w.w = (unsigned)__shfl((int)pk[s].w, src);
            afr[s] = __builtin_bit_cast(bf16x8, w);
        }
    };

    uint4 pk[4];
    bf16x8 afr[4];

    // ================= MLP 0: ea (attention bias, cols padded 8->16) ========
    float eaacc[4];
    first_layer(0, pk);
    gather_afr(pk, afr);
    {
        f32x4 acc = {0.f, 0.f, 0.f, 0.f};
        #pragma unroll
        for (int s = 0; s < 4; ++s) {
            const bf16x8 bfr = *(const bf16x8*)(easw + (size_t)(s * 64 + l) * 8);
            acc = __builtin_amdgcn_mfma_f32_16x16x32_bf16(afr[s], bfr, acc, 0, 0, 0);
        }
        #pragma unroll
        for (int r = 0; r < 4; ++r) eaacc[r] = acc[r];   // raw; bias added later
    }

    // ================= MLP 1: ek -> scores -> exp -> ex_ws ==================
    first_layer(1, pk);
    gather_afr(pk, afr);
    #pragma unroll
    for (int nt = 0; nt < NHEAD; ++nt) {
        f32x4 acc = {0.f, 0.f, 0.f, 0.f};
        #pragma unroll
        for (int s = 0; s < 4; ++s) {
            const bf16x8 bfr = *(const bf16x8*)(eksw + (size_t)((nt * 4 + s) * 64 + l) * 8);
            acc = __builtin_amdgcn_mfma_f32_16x16x32_bf16(afr[s], bfr, acc, 0, 0, 0);
        }
        const int col = nt * 16 + colb;
        const float b2 = pb2k[col];
        const float ba = pb2a[nt];
        float pr[4];
        #pragma unroll
        for (int r = 0; r < 4; ++r)
            pr[r] = (acc[r] + b2 + bf2f(k16[(size_t)tn[r] * D + col]))
                    * bf2f(q16[(size_t)hnn[r] * D + col]);
        #pragma unroll
        for (int m = 1; m < 16; m <<= 1) {
            #pragma unroll
            for (int r = 0; r < 4; ++r) pr[r] += __shfl_xor(pr[r], m);
        }
        #pragma unroll
        for (int r = 0; r < 4; ++r) {
            // segment-max skipped: |score| small, exp cannot overflow.
            const float ea = __shfl(eaacc[r], bsrc | nt);
            const float ex = __expf(pr[r] + ea + ba);
            if (colb == nt)
                ex_ws[(size_t)(e0g + mt*16 + row0 + r) * NHEAD + nt] = ex;
        }
    }

    // ================= MLP 2: ev -> raw vs (bf16) ===========================
    first_layer(2, pk);
    gather_afr(pk, afr);
    #pragma unroll
    for (int nt = 0; nt < NHEAD; ++nt) {
        f32x4 acc = {0.f, 0.f, 0.f, 0.f};
        #pragma unroll
        for (int s = 0; s < 4; ++s) {
            const bf16x8 bfr = *(const bf16x8*)(evsw + (size_t)((nt * 4 + s) * 64 + l) * 8);
            acc = __builtin_amdgcn_mfma_f32_16x16x32_bf16(afr[s], bfr, acc, 0, 0, 0);
        }
        const int col = nt * 16 + colb;
        const float b2 = pb2v[col];
        #pragma unroll
        for (int r = 0; r < 4; ++r) {
            const float vs = acc[r] + b2 + bf2f(v16[(size_t)tn[r] * D + col]);
            vs_ws[(size_t)(e0g + mt*16 + row0 + r) * D + col] = f2bf(vs);
        }
    }
}

// ---------------------------------------------------------------------------
// agg_out: 512 threads, 16 nodes per block, 4 row-groups (4 nodes each).
// Phase 1: stream each node's contiguous sorted segment of (ex, vs) -> LDS y.
// Phase 2: project y @ W + b (each row-group does 4 output rows).
// ---------------------------------------------------------------------------
__global__ __launch_bounds__(512, 8) void agg_out(
    const int* __restrict__ base,
    const float* __restrict__ ex_ws, const ushort_t* __restrict__ vs_ws,
    const float* __restrict__ W, const float* __restrict__ bias,
    float* __restrict__ out)
{
    __shared__ float xs[D][20];
    const int t  = threadIdx.x;
    const int rg = t >> 7;          // 0..3: node/row group
    const int j  = t & 127;
    const int h  = j >> 4;
    const int n0 = blockIdx.x * 16;

    // ---- phase 1: per-node segmented reduction (contiguous, no indices) ----
    #pragma unroll
    for (int ni = 0; ni < 4; ++ni) {
        const int n  = n0 + rg * 4 + ni;
        const int s0 = base[n], s1 = base[n + 1];
        float acc = 0.f, den = 0.f;
        int p = s0;
        for (; p + 4 <= s1; p += 4) {
            float ex4[4], vs4[4];
            #pragma unroll
            for (int r = 0; r < 4; ++r) {
                ex4[r] = ex_ws[(size_t)(p + r) * NHEAD + h];
                vs4[r] = bf2f(vs_ws[(size_t)(p + r) * D + j]);
            }
            #pragma unroll
            for (int r = 0; r < 4; ++r) {
                den += ex4[r];
                acc = fmaf(ex4[r], vs4[r], acc);
            }
        }
        for (; p < s1; ++p) {
            const float ex = ex_ws[(size_t)p * NHEAD + h];
            den += ex;
            acc = fmaf(ex, bf2f(vs_ws[(size_t)p * D + j]), acc);
        }
        xs[j][rg * 4 + ni] = acc / (den + EPS_SM);
    }
    __syncthreads();

    // ---- phase 2: out projection; row-group rg does rows rg*4..rg*4+4 ------
    float acc[4];
    const float b = bias[j];
    #pragma unroll
    for (int r = 0; r < 4; ++r) acc[r] = b;
    #pragma unroll 4
    for (int i = 0; i < D; ++i) {
        const float w = W[i * D + j];
        const float4 y4 = *(const float4*)&xs[i][rg * 4];
        acc[0] = fmaf(y4.x, w, acc[0]); acc[1] = fmaf(y4.y, w, acc[1]);
        acc[2] = fmaf(y4.z, w, acc[2]); acc[3] = fmaf(y4.w, w, acc[3]);
    }
    #pragma unroll
    for (int r = 0; r < 4; ++r)
        out[(size_t)(n0 + rg * 4 + r) * D + j] = acc[r];
}

// ---------------------------------------------------------------------------
extern "C" void kernel_launch(void* const* d_in, const int* in_sizes, int n_in,
                              void* d_out, int out_size, void* d_ws, size_t ws_size,
                              hipStream_t stream)
{
    const float* key        = (const float*)d_in[0];
    const float* value      = (const float*)d_in[1];
    const float* query      = (const float*)d_in[2];
    const float* edge_feats = (const float*)d_in[3];
    const int*   bidx       = (const int*)d_in[5];
    const int*   hidx       = (const int*)d_in[6];
    const int*   tidx       = (const int*)d_in[7];
    const float* key_w   = (const float*)d_in[8];  const float* key_b   = (const float*)d_in[9];
    const float* query_w = (const float*)d_in[10]; const float* query_b = (const float*)d_in[11];
    const float* value_w = (const float*)d_in[12]; const float* value_b = (const float*)d_in[13];
    const float* proj_w  = (const float*)d_in[14]; const float* proj_b  = (const float*)d_in[15];

    const int N = in_sizes[0] / D;   // 16384 nodes
    const int E = in_sizes[5];       // 262144 edges

    char* ws = (char*)d_ws;
    ushort_t* k16   = (ushort_t*)ws; ws += (size_t)N * D * 2;
    ushort_t* q16   = (ushort_t*)ws; ws += (size_t)N * D * 2;
    ushort_t* v16   = (ushort_t*)ws; ws += (size_t)N * D * 2;
    float* ex_ws    = (float*)ws;    ws += (size_t)E * NHEAD * 4;
    ushort_t* vs_ws = (ushort_t*)ws; ws += (size_t)E * D * 2;
    float* rec      = (float*)ws;    ws += (size_t)E * 8 * 4;
    ushort_t* eksw  = (ushort_t*)ws; ws += (size_t)2048 * 8 * 2;
    ushort_t* evsw  = (ushort_t*)ws; ws += (size_t)2048 * 8 * 2;
    ushort_t* easw  = (ushort_t*)ws; ws += (size_t)256 * 8 * 2;
    int* base = (int*)ws;  ws += (size_t)(N + 1) * 4;
    int* cnt  = (int*)ws;  ws += (size_t)N * 4;

    const int nqb   = N / 32;             // qkv blocks per matrix (512)
    const int nhist = (E + 255) / 256;    // 1024
    const int ngrid = 3 * nqb + 17 + nhist;

    hipMemsetAsync(cnt, 0, (size_t)N * 4, stream);

    setup_kernel<<<ngrid, 256, 0, stream>>>(
        key, value, query,
        key_w, key_b, value_w, value_b, query_w, query_b,
        k16, v16, q16,
        (const float*)d_in[26], (const float*)d_in[32], (const float*)d_in[20],
        eksw, evsw, easw,
        bidx, hidx, cnt, nqb, E);

    scan16k<<<1, 1024, 0, stream>>>(cnt, base);

    scatter_rec<<<(E + 255) / 256, 256, 0, stream>>>(
        bidx, hidx, tidx, edge_feats, base, cnt, rec, E);

    edge_kernel<<<E / EPB, 256, 0, stream>>>(
        rec,
        (const float*)d_in[16], (const float*)d_in[17], (const float*)d_in[18],
        (const float*)d_in[19], (const float*)d_in[21],
        (const float*)d_in[22], (const float*)d_in[23], (const float*)d_in[24],
        (const float*)d_in[25], (const float*)d_in[27],
        (const float*)d_in[28], (const float*)d_in[29], (const float*)d_in[30],
        (const float*)d_in[31], (const float*)d_in[33],
        easw, eksw, evsw,
        k16, q16, v16,
        ex_ws, vs_ws);

    agg_out<<<N / 16, 512, 0, stream>>>(base, ex_ws, vs_ws, proj_w, proj_b, (float*)d_out);
}

// Round 10
// 433.688 us; speedup vs baseline: 1.2367x; 1.2367x over previous
//
#include <hip/hip_runtime.h>
#include <hip/hip_bf16.h>

#define D      128
#define NHEAD  8
#define FE     5
#define LSEQ   4096
#define EPB    64          // edges per block in edge_kernel
#define NNODE  16384
#define EPS_LN 1e-5f
#define EPS_SM 1e-16f

typedef unsigned short ushort_t;
typedef __bf16 bf16x8 __attribute__((ext_vector_type(8)));
typedef float  f32x4  __attribute__((ext_vector_type(4)));

__device__ __forceinline__ ushort_t f2bf(float x) {
    __hip_bfloat16 b = __float2bfloat16(x);
    return __builtin_bit_cast(unsigned short, b);
}
__device__ __forceinline__ float bf2f(ushort_t u) {
    __hip_bfloat16 b = __builtin_bit_cast(__hip_bfloat16, u);
    return __bfloat162float(b);
}
__device__ __forceinline__ float i2f(int x)  { return __builtin_bit_cast(float, x); }
__device__ __forceinline__ int   f2i(float x){ return __builtin_bit_cast(int, x); }

union Pk8 { ushort_t u[8]; uint4 v; };

// ---------------------------------------------------------------------------
// setup_kernel: independent jobs partitioned by blockIdx
//   [0, 3*nqb)        : qkv GEMMs, 32 rows/block, bf16 output
//   [3*nqb, +17)      : w2 swizzle into MFMA B-fragment layout
//   [3*nqb+17, +1024) : head histogram (cnt pre-zeroed by memset)
// NOTE: no in-kernel scan/fence — 1024 device-scope fences cost ~100 µs (R7).
// ---------------------------------------------------------------------------
__global__ __launch_bounds__(256) void setup_kernel(
    const float* __restrict__ key, const float* __restrict__ value,
    const float* __restrict__ query,
    const float* __restrict__ key_w, const float* __restrict__ key_b,
    const float* __restrict__ value_w, const float* __restrict__ value_b,
    const float* __restrict__ query_w, const float* __restrict__ query_b,
    ushort_t* __restrict__ k16, ushort_t* __restrict__ v16, ushort_t* __restrict__ q16,
    const float* __restrict__ ekw2, const float* __restrict__ evw2,
    const float* __restrict__ eaw2,
    ushort_t* __restrict__ eksw, ushort_t* __restrict__ evsw, ushort_t* __restrict__ easw,
    const int* __restrict__ bidx, const int* __restrict__ hidx,
    int* __restrict__ cnt, int nqb, int E)
{
    const int t  = threadIdx.x;
    const int nq = 3 * nqb;

    if ((int)blockIdx.x < nq) {
        // ---------------- qkv GEMM: [Nx128]@[128x128], 32 rows/block --------
        __shared__ float xs[2][D][20];
        const int which = blockIdx.x / nqb;
        const int r0    = (blockIdx.x % nqb) * 32;
        const float* X = (which == 0) ? key   : (which == 1) ? value   : query;
        const float* W = (which == 0) ? key_w : (which == 1) ? value_w : query_w;
        const float* bias = (which == 0) ? key_b : (which == 1) ? value_b : query_b;
        ushort_t* Y = (which == 0) ? k16 : (which == 1) ? v16 : q16;

        const int rg = t >> 7, j = t & 127;
        const int rbase = r0 + rg * 16;
        {
            float tmp[16];
            #pragma unroll
            for (int r = 0; r < 16; ++r) tmp[r] = X[(size_t)(rbase + r) * D + j];
            #pragma unroll
            for (int c = 0; c < 4; ++c)
                *(float4*)&xs[rg][j][c * 4] = float4{tmp[c*4], tmp[c*4+1], tmp[c*4+2], tmp[c*4+3]};
        }
        __syncthreads();
        float acc[16];
        const float b = bias[j];
        #pragma unroll
        for (int r = 0; r < 16; ++r) acc[r] = b;
        #pragma unroll 4
        for (int i = 0; i < D; ++i) {
            const float w = W[i * D + j];
            #pragma unroll
            for (int c = 0; c < 4; ++c) {
                const float4 x4 = *(const float4*)&xs[rg][i][c * 4];
                acc[c*4+0] = fmaf(x4.x, w, acc[c*4+0]);
                acc[c*4+1] = fmaf(x4.y, w, acc[c*4+1]);
                acc[c*4+2] = fmaf(x4.z, w, acc[c*4+2]);
                acc[c*4+3] = fmaf(x4.w, w, acc[c*4+3]);
            }
        }
        #pragma unroll
        for (int r = 0; r < 16; ++r) Y[(size_t)(rbase + r) * D + j] = f2bf(acc[r]);
        return;
    }

    const int b2 = blockIdx.x - nq;
    if (b2 < 17) {
        // ---------------- w2 swizzle --------------------------------------
        const int g = b2 * 256 + t;
        const float* src; ushort_t* dst; int frag, ncols, nvalid;
        if (g < 2048)      { src = ekw2; dst = eksw; frag = g;        ncols = 128; nvalid = 128; }
        else if (g < 4096) { src = evw2; dst = evsw; frag = g - 2048; ncols = 128; nvalid = 128; }
        else if (g < 4352) { src = eaw2; dst = easw; frag = g - 4096; ncols = 8;   nvalid = 8; }
        else return;
        const int s = (frag >> 6) & 3;
        const int l = frag & 63;
        const int n = ((frag >> 8) << 4) + (l & 15);
        Pk8 pk;
        #pragma unroll
        for (int j = 0; j < 8; ++j) {
            const int k = s * 32 + (l >> 4) * 8 + j;
            const float v = (n < nvalid) ? src[k * ncols + n] : 0.f;
            pk.u[j] = f2bf(v);
        }
        *(uint4*)(dst + (size_t)frag * 8) = pk.v;
        return;
    }

    // ---------------- histogram ------------------------------------------
    const int e = (b2 - 17) * 256 + t;
    if (e < E) atomicAdd(&cnt[bidx[e] * LSEQ + hidx[e]], 1);
}

// ---------------------------------------------------------------------------
// Exclusive scan of the 16384-bin histogram (single block, ~5 µs).
// ---------------------------------------------------------------------------
__global__ __launch_bounds__(1024) void scan16k(
    const int* __restrict__ cnt, int* __restrict__ base)
{
    __shared__ int part[1024];
    const int t = threadIdx.x;
    int v[16], ex[16], s = 0;
    #pragma unroll
    for (int i = 0; i < 16; ++i) v[i] = cnt[t * 16 + i];
    #pragma unroll
    for (int i = 0; i < 16; ++i) { ex[i] = s; s += v[i]; }
    part[t] = s;
    __syncthreads();
    for (int off = 1; off < 1024; off <<= 1) {
        const int x = (t >= off) ? part[t - off] : 0;
        __syncthreads();
        part[t] += x;
        __syncthreads();
    }
    const int boff = (t > 0) ? part[t - 1] : 0;
    #pragma unroll
    for (int i = 0; i < 16; ++i) base[t * 16 + i] = boff + ex[i];
    if (t == 1023) base[NNODE] = boff + s;
}

// ---------------------------------------------------------------------------
// scatter_rec: assign each edge its sorted slot p and write a packed 32 B
// record rec[p] = {ef[5], head_node, tail_node, pad}. Edge kernel then
// reads rec[] fully coalesced despite the permutation.
// ---------------------------------------------------------------------------
__global__ __launch_bounds__(256) void scatter_rec(
    const int* __restrict__ bidx, const int* __restrict__ hidx, const int* __restrict__ tidx,
    const float* __restrict__ edge_feats,
    const int* __restrict__ base, int* __restrict__ cnt,
    float* __restrict__ rec, int E)
{
    const int e = blockIdx.x * 256 + threadIdx.x;
    if (e >= E) return;
    const int bb = bidx[e];
    const int nh = bb * LSEQ + hidx[e];
    const int nt = bb * LSEQ + tidx[e];
    const int slot = atomicSub(&cnt[nh], 1) - 1;
    const int p = base[nh] + slot;
    float ef[FE];
    #pragma unroll
    for (int f = 0; f < FE; ++f) ef[f] = edge_feats[(size_t)e * FE + f];
    *(float4*)&rec[(size_t)p * 8]     = float4{ef[0], ef[1], ef[2], ef[3]};
    *(float4*)&rec[(size_t)p * 8 + 4] = float4{ef[4], i2f(nh), i2f(nt), 0.f};
}

// ---------------------------------------------------------------------------
// Fused edge kernel — barrier-free wave-local pipeline over SORTED positions.
// Block b handles p in [b*64, b*64+64); all edge data from rec[] (coalesced).
// Writes ex (f32 [p][8]) and vs (bf16 [p][128]) at sorted positions.
// __launch_bounds__(256,6): VGPR cap 85 >= natural 64 (NO spill — R9 showed
// (256,8) forces VGPR 32 -> 1.4 GB scratch traffic, 3x regression).
// ---------------------------------------------------------------------------
__global__ __launch_bounds__(256, 6) void edge_kernel(
    const float* __restrict__ rec,
    const float* __restrict__ ea_w1, const float* __restrict__ ea_b1,
    const float* __restrict__ ea_g,  const float* __restrict__ ea_be, const float* __restrict__ ea_b2,
    const float* __restrict__ ek_w1, const float* __restrict__ ek_b1,
    const float* __restrict__ ek_g,  const float* __restrict__ ek_be, const float* __restrict__ ek_b2,
    const float* __restrict__ ev_w1, const float* __restrict__ ev_b1,
    const float* __restrict__ ev_g,  const float* __restrict__ ev_be, const float* __restrict__ ev_b2,
    const ushort_t* __restrict__ easw, const ushort_t* __restrict__ eksw, const ushort_t* __restrict__ evsw,
    const ushort_t* __restrict__ k16, const ushort_t* __restrict__ q16, const ushort_t* __restrict__ v16,
    float* __restrict__ ex_ws, ushort_t* __restrict__ vs_ws)
{
    __shared__ float pw1[3][FE * D];
    __shared__ float pb1[3][D], pg[3][D], pbe[3][D];
    __shared__ float pb2k[D], pb2v[D], pb2a[NHEAD];
    __shared__ float ef_s[EPB][FE];
    __shared__ int   eh_s[EPB], et_s[EPB];

    const int t   = threadIdx.x;
    const int e0g = blockIdx.x * EPB;   // sorted-position base

    for (int i = t; i < FE * D; i += 256) { pw1[0][i] = ea_w1[i]; pw1[1][i] = ek_w1[i]; pw1[2][i] = ev_w1[i]; }
    if (t < D) {
        pb1[0][t] = ea_b1[t]; pb1[1][t] = ek_b1[t]; pb1[2][t] = ev_b1[t];
        pg [0][t] = ea_g [t]; pg [1][t] = ek_g [t]; pg [2][t] = ev_g [t];
        pbe[0][t] = ea_be[t]; pbe[1][t] = ek_be[t]; pbe[2][t] = ev_be[t];
        pb2k[t] = ek_b2[t];   pb2v[t] = ev_b2[t];
        if (t < NHEAD) pb2a[t] = ea_b2[t];
    }
    if (t < 128) {
        const int pl = t >> 1, half = t & 1;
        const float4 v = *(const float4*)&rec[((size_t)e0g + pl) * 8 + half * 4];
        if (half == 0) {
            ef_s[pl][0] = v.x; ef_s[pl][1] = v.y; ef_s[pl][2] = v.z; ef_s[pl][3] = v.w;
        } else {
            ef_s[pl][4] = v.x; eh_s[pl] = f2i(v.y); et_s[pl] = f2i(v.z);
        }
    }
    __syncthreads();     // the only barrier

    const int mt   = t >> 6;        // wave id == m-tile
    const int l    = t & 63;        // lane
    const int qt   = l & 3;         // producer: dim-chunk quarter
    const int per  = l >> 2;        // producer: edge row 0..15
    const int row0 = (l >> 4) * 4;  // consumer: accumulator row base
    const int colb = l & 15;        // consumer: column within n-tile
    const int src  = 4 * colb + (l >> 4);   // shfl source for A-frag chunks
    const int bsrc = (l & 48);      // row-group base for ea broadcasts

    int tn[4], hnn[4];
    #pragma unroll
    for (int r = 0; r < 4; ++r) { tn[r] = et_s[mt*16 + row0 + r]; hnn[r] = eh_s[mt*16 + row0 + r]; }

    float efr[FE];
    #pragma unroll
    for (int f = 0; f < FE; ++f) efr[f] = ef_s[mt*16 + per][f];

    auto first_layer = [&](int m, uint4 pk[4]) {
        const float4* w1v = (const float4*)&pw1[m][0];
        const float4* b1v = (const float4*)&pb1[m][0];
        const float4* gv  = (const float4*)&pg[m][0];
        const float4* bev = (const float4*)&pbe[m][0];
        float4 hv[4][2];
        float s1 = 0.f, s2 = 0.f;
        #pragma unroll
        for (int s = 0; s < 4; ++s) {
            #pragma unroll
            for (int hc = 0; hc < 2; ++hc) {
                const int idx = s * 8 + qt * 2 + hc;
                float4 a = b1v[idx];
                #pragma unroll
                for (int f = 0; f < FE; ++f) {
                    const float sc = efr[f];
                    const float4 w = w1v[f * 32 + idx];
                    a.x = fmaf(sc, w.x, a.x); a.y = fmaf(sc, w.y, a.y);
                    a.z = fmaf(sc, w.z, a.z); a.w = fmaf(sc, w.w, a.w);
                }
                a.x = fmaxf(a.x, 0.f); a.y = fmaxf(a.y, 0.f);
                a.z = fmaxf(a.z, 0.f); a.w = fmaxf(a.w, 0.f);
                hv[s][hc] = a;
                s1 += a.x + a.y + a.z + a.w;
                s2 += a.x*a.x + a.y*a.y + a.z*a.z + a.w*a.w;
            }
        }
        s1 += __shfl_xor(s1, 1); s1 += __shfl_xor(s1, 2);
        s2 += __shfl_xor(s2, 1); s2 += __shfl_xor(s2, 2);
        const float mu = s1 * (1.f / 128.f);
        const float rs = rsqrtf(s2 * (1.f / 128.f) - mu * mu + EPS_LN);
        #pragma unroll
        for (int s = 0; s < 4; ++s) {
            const int idx = s * 8 + qt * 2;
            const float4 x0 = hv[s][0], x1 = hv[s][1];
            const float4 g0 = gv[idx], g1 = gv[idx + 1];
            const float4 b0 = bev[idx], b1 = bev[idx + 1];
            Pk8 p8;
            p8.u[0] = f2bf(fmaf((x0.x - mu) * rs, g0.x, b0.x));
            p8.u[1] = f2bf(fmaf((x0.y - mu) * rs, g0.y, b0.y));
            p8.u[2] = f2bf(fmaf((x0.z - mu) * rs, g0.z, b0.z));
            p8.u[3] = f2bf(fmaf((x0.w - mu) * rs, g0.w, b0.w));
            p8.u[4] = f2bf(fmaf((x1.x - mu) * rs, g1.x, b1.x));
            p8.u[5] = f2bf(fmaf((x1.y - mu) * rs, g1.y, b1.y));
            p8.u[6] = f2bf(fmaf((x1.z - mu) * rs, g1.z, b1.z));
            p8.u[7] = f2bf(fmaf((x1.w - mu) * rs, g1.w, b1.w));
            pk[s] = p8.v;
        }
    };

    auto gather_afr = [&](const uint4 pk[4], bf16x8 afr[4]) {
        #pragma unroll
        for (int s = 0; s < 4; ++s) {
            uint4 w;
            w.x = (unsigned)__shfl((int)pk[s].x, src);
            w.y = (unsigned)__shfl((int)pk[s].y, src);
            w.z = (unsigned)__shfl((int)pk[s].z, src);
            w.w = (unsigned)__shfl((int)pk[s].w, src);
            afr[s] = __builtin_bit_cast(bf16x8, w);
        }
    };

    uint4 pk[4];
    bf16x8 afr[4];

    // ================= MLP 0: ea (attention bias, cols padded 8->16) ========
    float eaacc[4];
    first_layer(0, pk);
    gather_afr(pk, afr);
    {
        f32x4 acc = {0.f, 0.f, 0.f, 0.f};
        #pragma unroll
        for (int s = 0; s < 4; ++s) {
            const bf16x8 bfr = *(const bf16x8*)(easw + (size_t)(s * 64 + l) * 8);
            acc = __builtin_amdgcn_mfma_f32_16x16x32_bf16(afr[s], bfr, acc, 0, 0, 0);
        }
        #pragma unroll
        for (int r = 0; r < 4; ++r) eaacc[r] = acc[r];   // raw; bias added later
    }

    // ================= MLP 1: ek -> scores -> exp -> ex_ws ==================
    first_layer(1, pk);
    gather_afr(pk, afr);
    #pragma unroll
    for (int nt = 0; nt < NHEAD; ++nt) {
        f32x4 acc = {0.f, 0.f, 0.f, 0.f};
        #pragma unroll
        for (int s = 0; s < 4; ++s) {
            const bf16x8 bfr = *(const bf16x8*)(eksw + (size_t)((nt * 4 + s) * 64 + l) * 8);
            acc = __builtin_amdgcn_mfma_f32_16x16x32_bf16(afr[s], bfr, acc, 0, 0, 0);
        }
        const int col = nt * 16 + colb;
        const float b2 = pb2k[col];
        const float ba = pb2a[nt];
        float pr[4];
        #pragma unroll
        for (int r = 0; r < 4; ++r)
            pr[r] = (acc[r] + b2 + bf2f(k16[(size_t)tn[r] * D + col]))
                    * bf2f(q16[(size_t)hnn[r] * D + col]);
        #pragma unroll
        for (int m = 1; m < 16; m <<= 1) {
            #pragma unroll
            for (int r = 0; r < 4; ++r) pr[r] += __shfl_xor(pr[r], m);
        }
        #pragma unroll
        for (int r = 0; r < 4; ++r) {
            // segment-max skipped: |score| small, exp cannot overflow.
            const float ea = __shfl(eaacc[r], bsrc | nt);
            const float ex = __expf(pr[r] + ea + ba);
            if (colb == nt)
                ex_ws[(size_t)(e0g + mt*16 + row0 + r) * NHEAD + nt] = ex;
        }
    }

    // ================= MLP 2: ev -> raw vs (bf16) ===========================
    first_layer(2, pk);
    gather_afr(pk, afr);
    #pragma unroll
    for (int nt = 0; nt < NHEAD; ++nt) {
        f32x4 acc = {0.f, 0.f, 0.f, 0.f};
        #pragma unroll
        for (int s = 0; s < 4; ++s) {
            const bf16x8 bfr = *(const bf16x8*)(evsw + (size_t)((nt * 4 + s) * 64 + l) * 8);
            acc = __builtin_amdgcn_mfma_f32_16x16x32_bf16(afr[s], bfr, acc, 0, 0, 0);
        }
        const int col = nt * 16 + colb;
        const float b2 = pb2v[col];
        #pragma unroll
        for (int r = 0; r < 4; ++r) {
            const float vs = acc[r] + b2 + bf2f(v16[(size_t)tn[r] * D + col]);
            vs_ws[(size_t)(e0g + mt*16 + row0 + r) * D + col] = f2bf(vs);
        }
    }
}

// ---------------------------------------------------------------------------
// agg_out: 512 threads, 16 nodes per block, 4 row-groups (4 nodes each).
// Phase 1: stream each node's contiguous sorted segment of (ex, vs) -> LDS y.
// Phase 2: project y @ W + b (each row-group does 4 output rows).
// (512,4): generous VGPR cap (128) — do not squeeze the allocator (R9).
// ---------------------------------------------------------------------------
__global__ __launch_bounds__(512, 4) void agg_out(
    const int* __restrict__ base,
    const float* __restrict__ ex_ws, const ushort_t* __restrict__ vs_ws,
    const float* __restrict__ W, const float* __restrict__ bias,
    float* __restrict__ out)
{
    __shared__ float xs[D][20];
    const int t  = threadIdx.x;
    const int rg = t >> 7;          // 0..3: node/row group
    const int j  = t & 127;
    const int h  = j >> 4;
    const int n0 = blockIdx.x * 16;

    // ---- phase 1: per-node segmented reduction (contiguous, no indices) ----
    #pragma unroll
    for (int ni = 0; ni < 4; ++ni) {
        const int n  = n0 + rg * 4 + ni;
        const int s0 = base[n], s1 = base[n + 1];
        float acc = 0.f, den = 0.f;
        int p = s0;
        for (; p + 4 <= s1; p += 4) {
            float ex4[4], vs4[4];
            #pragma unroll
            for (int r = 0; r < 4; ++r) {
                ex4[r] = ex_ws[(size_t)(p + r) * NHEAD + h];
                vs4[r] = bf2f(vs_ws[(size_t)(p + r) * D + j]);
            }
            #pragma unroll
            for (int r = 0; r < 4; ++r) {
                den += ex4[r];
                acc = fmaf(ex4[r], vs4[r], acc);
            }
        }
        for (; p < s1; ++p) {
            const float ex = ex_ws[(size_t)p * NHEAD + h];
            den += ex;
            acc = fmaf(ex, bf2f(vs_ws[(size_t)p * D + j]), acc);
        }
        xs[j][rg * 4 + ni] = acc / (den + EPS_SM);
    }
    __syncthreads();

    // ---- phase 2: out projection; row-group rg does rows rg*4..rg*4+4 ------
    float acc[4];
    const float b = bias[j];
    #pragma unroll
    for (int r = 0; r < 4; ++r) acc[r] = b;
    #pragma unroll 4
    for (int i = 0; i < D; ++i) {
        const float w = W[i * D + j];
        const float4 y4 = *(const float4*)&xs[i][rg * 4];
        acc[0] = fmaf(y4.x, w, acc[0]); acc[1] = fmaf(y4.y, w, acc[1]);
        acc[2] = fmaf(y4.z, w, acc[2]); acc[3] = fmaf(y4.w, w, acc[3]);
    }
    #pragma unroll
    for (int r = 0; r < 4; ++r)
        out[(size_t)(n0 + rg * 4 + r) * D + j] = acc[r];
}

// ---------------------------------------------------------------------------
extern "C" void kernel_launch(void* const* d_in, const int* in_sizes, int n_in,
                              void* d_out, int out_size, void* d_ws, size_t ws_size,
                              hipStream_t stream)
{
    const float* key        = (const float*)d_in[0];
    const float* value      = (const float*)d_in[1];
    const float* query      = (const float*)d_in[2];
    const float* edge_feats = (const float*)d_in[3];
    const int*   bidx       = (const int*)d_in[5];
    const int*   hidx       = (const int*)d_in[6];
    const int*   tidx       = (const int*)d_in[7];
    const float* key_w   = (const float*)d_in[8];  const float* key_b   = (const float*)d_in[9];
    const float* query_w = (const float*)d_in[10]; const float* query_b = (const float*)d_in[11];
    const float* value_w = (const float*)d_in[12]; const float* value_b = (const float*)d_in[13];
    const float* proj_w  = (const float*)d_in[14]; const float* proj_b  = (const float*)d_in[15];

    const int N = in_sizes[0] / D;   // 16384 nodes
    const int E = in_sizes[5];       // 262144 edges

    char* ws = (char*)d_ws;
    ushort_t* k16   = (ushort_t*)ws; ws += (size_t)N * D * 2;
    ushort_t* q16   = (ushort_t*)ws; ws += (size_t)N * D * 2;
    ushort_t* v16   = (ushort_t*)ws; ws += (size_t)N * D * 2;
    float* ex_ws    = (float*)ws;    ws += (size_t)E * NHEAD * 4;
    ushort_t* vs_ws = (ushort_t*)ws; ws += (size_t)E * D * 2;
    float* rec      = (float*)ws;    ws += (size_t)E * 8 * 4;
    ushort_t* eksw  = (ushort_t*)ws; ws += (size_t)2048 * 8 * 2;
    ushort_t* evsw  = (ushort_t*)ws; ws += (size_t)2048 * 8 * 2;
    ushort_t* easw  = (ushort_t*)ws; ws += (size_t)256 * 8 * 2;
    int* base = (int*)ws;  ws += (size_t)(N + 1) * 4;
    int* cnt  = (int*)ws;  ws += (size_t)N * 4;

    const int nqb   = N / 32;             // qkv blocks per matrix (512)
    const int nhist = (E + 255) / 256;    // 1024
    const int ngrid = 3 * nqb + 17 + nhist;

    hipMemsetAsync(cnt, 0, (size_t)N * 4, stream);

    setup_kernel<<<ngrid, 256, 0, stream>>>(
        key, value, query,
        key_w, key_b, value_w, value_b, query_w, query_b,
        k16, v16, q16,
        (const float*)d_in[26], (const float*)d_in[32], (const float*)d_in[20],
        eksw, evsw, easw,
        bidx, hidx, cnt, nqb, E);

    scan16k<<<1, 1024, 0, stream>>>(cnt, base);

    scatter_rec<<<(E + 255) / 256, 256, 0, stream>>>(
        bidx, hidx, tidx, edge_feats, base, cnt, rec, E);

    edge_kernel<<<E / EPB, 256, 0, stream>>>(
        rec,
        (const float*)d_in[16], (const float*)d_in[17], (const float*)d_in[18],
        (const float*)d_in[19], (const float*)d_in[21],
        (const float*)d_in[22], (const float*)d_in[23], (const float*)d_in[24],
        (const float*)d_in[25], (const float*)d_in[27],
        (const float*)d_in[28], (const float*)d_in[29], (const float*)d_in[30],
        (const float*)d_in[31], (const float*)d_in[33],
        easw, eksw, evsw,
        k16, q16, v16,
        ex_ws, vs_ws);

    agg_out<<<N / 16, 512, 0, stream>>>(base, ex_ws, vs_ws, proj_w, proj_b, (float*)d_out);
}

// Round 11
// 311.368 us; speedup vs baseline: 1.7225x; 1.3928x over previous
//
#include <hip/hip_runtime.h>
#include <hip/hip_bf16.h>

#define D      128
#define NHEAD  8
#define FE     5
#define LSEQ   4096
#define EPB    64          // edges per block in edge_kernel
#define NNODE  16384
#define EPS_LN 1e-5f
#define EPS_SM 1e-16f

typedef unsigned short ushort_t;
typedef __bf16 bf16x8 __attribute__((ext_vector_type(8)));
typedef float  f32x4  __attribute__((ext_vector_type(4)));

__device__ __forceinline__ ushort_t f2bf(float x) {
    __hip_bfloat16 b = __float2bfloat16(x);
    return __builtin_bit_cast(unsigned short, b);
}
__device__ __forceinline__ float bf2f(ushort_t u) {
    __hip_bfloat16 b = __builtin_bit_cast(__hip_bfloat16, u);
    return __bfloat162float(b);
}
__device__ __forceinline__ float i2f(int x)  { return __builtin_bit_cast(float, x); }
__device__ __forceinline__ int   f2i(float x){ return __builtin_bit_cast(int, x); }

union Pk8 { ushort_t u[8]; uint4 v; };

// ---------------------------------------------------------------------------
// setup_kernel: independent jobs partitioned by blockIdx
//   [0, 3*nqb)        : qkv GEMMs, 32 rows/block, bf16 output
//   [3*nqb, +17)      : w2 swizzle into MFMA B-fragment layout
//   [3*nqb+17, +1024) : head histogram (cnt pre-zeroed by memset)
// NOTE: no in-kernel scan/fence — 1024 device-scope fences cost ~100 µs (R7).
// ---------------------------------------------------------------------------
__global__ __launch_bounds__(256) void setup_kernel(
    const float* __restrict__ key, const float* __restrict__ value,
    const float* __restrict__ query,
    const float* __restrict__ key_w, const float* __restrict__ key_b,
    const float* __restrict__ value_w, const float* __restrict__ value_b,
    const float* __restrict__ query_w, const float* __restrict__ query_b,
    ushort_t* __restrict__ k16, ushort_t* __restrict__ v16, ushort_t* __restrict__ q16,
    const float* __restrict__ ekw2, const float* __restrict__ evw2,
    const float* __restrict__ eaw2,
    ushort_t* __restrict__ eksw, ushort_t* __restrict__ evsw, ushort_t* __restrict__ easw,
    const int* __restrict__ bidx, const int* __restrict__ hidx,
    int* __restrict__ cnt, int nqb, int E)
{
    const int t  = threadIdx.x;
    const int nq = 3 * nqb;

    if ((int)blockIdx.x < nq) {
        // ---------------- qkv GEMM: [Nx128]@[128x128], 32 rows/block --------
        __shared__ float xs[2][D][20];
        const int which = blockIdx.x / nqb;
        const int r0    = (blockIdx.x % nqb) * 32;
        const float* X = (which == 0) ? key   : (which == 1) ? value   : query;
        const float* W = (which == 0) ? key_w : (which == 1) ? value_w : query_w;
        const float* bias = (which == 0) ? key_b : (which == 1) ? value_b : query_b;
        ushort_t* Y = (which == 0) ? k16 : (which == 1) ? v16 : q16;

        const int rg = t >> 7, j = t & 127;
        const int rbase = r0 + rg * 16;
        {
            float tmp[16];
            #pragma unroll
            for (int r = 0; r < 16; ++r) tmp[r] = X[(size_t)(rbase + r) * D + j];
            #pragma unroll
            for (int c = 0; c < 4; ++c)
                *(float4*)&xs[rg][j][c * 4] = float4{tmp[c*4], tmp[c*4+1], tmp[c*4+2], tmp[c*4+3]};
        }
        __syncthreads();
        float acc[16];
        const float b = bias[j];
        #pragma unroll
        for (int r = 0; r < 16; ++r) acc[r] = b;
        #pragma unroll 4
        for (int i = 0; i < D; ++i) {
            const float w = W[i * D + j];
            #pragma unroll
            for (int c = 0; c < 4; ++c) {
                const float4 x4 = *(const float4*)&xs[rg][i][c * 4];
                acc[c*4+0] = fmaf(x4.x, w, acc[c*4+0]);
                acc[c*4+1] = fmaf(x4.y, w, acc[c*4+1]);
                acc[c*4+2] = fmaf(x4.z, w, acc[c*4+2]);
                acc[c*4+3] = fmaf(x4.w, w, acc[c*4+3]);
            }
        }
        #pragma unroll
        for (int r = 0; r < 16; ++r) Y[(size_t)(rbase + r) * D + j] = f2bf(acc[r]);
        return;
    }

    const int b2 = blockIdx.x - nq;
    if (b2 < 17) {
        // ---------------- w2 swizzle --------------------------------------
        const int g = b2 * 256 + t;
        const float* src; ushort_t* dst; int frag, ncols, nvalid;
        if (g < 2048)      { src = ekw2; dst = eksw; frag = g;        ncols = 128; nvalid = 128; }
        else if (g < 4096) { src = evw2; dst = evsw; frag = g - 2048; ncols = 128; nvalid = 128; }
        else if (g < 4352) { src = eaw2; dst = easw; frag = g - 4096; ncols = 8;   nvalid = 8; }
        else return;
        const int s = (frag >> 6) & 3;
        const int l = frag & 63;
        const int n = ((frag >> 8) << 4) + (l & 15);
        Pk8 pk;
        #pragma unroll
        for (int j = 0; j < 8; ++j) {
            const int k = s * 32 + (l >> 4) * 8 + j;
            const float v = (n < nvalid) ? src[k * ncols + n] : 0.f;
            pk.u[j] = f2bf(v);
        }
        *(uint4*)(dst + (size_t)frag * 8) = pk.v;
        return;
    }

    // ---------------- histogram ------------------------------------------
    const int e = (b2 - 17) * 256 + t;
    if (e < E) atomicAdd(&cnt[bidx[e] * LSEQ + hidx[e]], 1);
}

// ---------------------------------------------------------------------------
// Exclusive scan of the 16384-bin histogram (single block, ~5 µs).
// ---------------------------------------------------------------------------
__global__ __launch_bounds__(1024) void scan16k(
    const int* __restrict__ cnt, int* __restrict__ base)
{
    __shared__ int part[1024];
    const int t = threadIdx.x;
    int v[16], ex[16], s = 0;
    #pragma unroll
    for (int i = 0; i < 16; ++i) v[i] = cnt[t * 16 + i];
    #pragma unroll
    for (int i = 0; i < 16; ++i) { ex[i] = s; s += v[i]; }
    part[t] = s;
    __syncthreads();
    for (int off = 1; off < 1024; off <<= 1) {
        const int x = (t >= off) ? part[t - off] : 0;
        __syncthreads();
        part[t] += x;
        __syncthreads();
    }
    const int boff = (t > 0) ? part[t - 1] : 0;
    #pragma unroll
    for (int i = 0; i < 16; ++i) base[t * 16 + i] = boff + ex[i];
    if (t == 1023) base[NNODE] = boff + s;
}

// ---------------------------------------------------------------------------
// scatter_rec: assign each edge its sorted slot p and write a packed 32 B
// record rec[p] = {ef[5], head_node, tail_node, pad}. Edge kernel then
// reads rec[] fully coalesced despite the permutation.
// ---------------------------------------------------------------------------
__global__ __launch_bounds__(256) void scatter_rec(
    const int* __restrict__ bidx, const int* __restrict__ hidx, const int* __restrict__ tidx,
    const float* __restrict__ edge_feats,
    const int* __restrict__ base, int* __restrict__ cnt,
    float* __restrict__ rec, int E)
{
    const int e = blockIdx.x * 256 + threadIdx.x;
    if (e >= E) return;
    const int bb = bidx[e];
    const int nh = bb * LSEQ + hidx[e];
    const int nt = bb * LSEQ + tidx[e];
    const int slot = atomicSub(&cnt[nh], 1) - 1;
    const int p = base[nh] + slot;
    float ef[FE];
    #pragma unroll
    for (int f = 0; f < FE; ++f) ef[f] = edge_feats[(size_t)e * FE + f];
    *(float4*)&rec[(size_t)p * 8]     = float4{ef[0], ef[1], ef[2], ef[3]};
    *(float4*)&rec[(size_t)p * 8 + 4] = float4{ef[4], i2f(nh), i2f(nt), 0.f};
}

// ---------------------------------------------------------------------------
// Fused edge kernel — barrier-free wave-local pipeline over SORTED positions.
// Block b handles p in [b*64, b*64+64); all edge data from rec[] (coalesced).
// Writes ex (f32 [p][8]) and vs (bf16 [p][128]) at sorted positions.
// __launch_bounds__(256,4): the ONLY no-spill config. R9 (256,8) -> VGPR 32,
// 1.4 GB scratch; R10 (256,6) -> VGPR 40, 0.85 GB scratch. Natural unified
// VGPR+AGPR footprint is ~128+/wave — do not raise the waves/EU contract.
// ---------------------------------------------------------------------------
__global__ __launch_bounds__(256, 4) void edge_kernel(
    const float* __restrict__ rec,
    const float* __restrict__ ea_w1, const float* __restrict__ ea_b1,
    const float* __restrict__ ea_g,  const float* __restrict__ ea_be, const float* __restrict__ ea_b2,
    const float* __restrict__ ek_w1, const float* __restrict__ ek_b1,
    const float* __restrict__ ek_g,  const float* __restrict__ ek_be, const float* __restrict__ ek_b2,
    const float* __restrict__ ev_w1, const float* __restrict__ ev_b1,
    const float* __restrict__ ev_g,  const float* __restrict__ ev_be, const float* __restrict__ ev_b2,
    const ushort_t* __restrict__ easw, const ushort_t* __restrict__ eksw, const ushort_t* __restrict__ evsw,
    const ushort_t* __restrict__ k16, const ushort_t* __restrict__ q16, const ushort_t* __restrict__ v16,
    float* __restrict__ ex_ws, ushort_t* __restrict__ vs_ws)
{
    __shared__ float pw1[3][FE * D];
    __shared__ float pb1[3][D], pg[3][D], pbe[3][D];
    __shared__ float pb2k[D], pb2v[D], pb2a[NHEAD];
    __shared__ float ef_s[EPB][FE];
    __shared__ int   eh_s[EPB], et_s[EPB];

    const int t   = threadIdx.x;
    const int e0g = blockIdx.x * EPB;   // sorted-position base

    for (int i = t; i < FE * D; i += 256) { pw1[0][i] = ea_w1[i]; pw1[1][i] = ek_w1[i]; pw1[2][i] = ev_w1[i]; }
    if (t < D) {
        pb1[0][t] = ea_b1[t]; pb1[1][t] = ek_b1[t]; pb1[2][t] = ev_b1[t];
        pg [0][t] = ea_g [t]; pg [1][t] = ek_g [t]; pg [2][t] = ev_g [t];
        pbe[0][t] = ea_be[t]; pbe[1][t] = ek_be[t]; pbe[2][t] = ev_be[t];
        pb2k[t] = ek_b2[t];   pb2v[t] = ev_b2[t];
        if (t < NHEAD) pb2a[t] = ea_b2[t];
    }
    if (t < 128) {
        const int pl = t >> 1, half = t & 1;
        const float4 v = *(const float4*)&rec[((size_t)e0g + pl) * 8 + half * 4];
        if (half == 0) {
            ef_s[pl][0] = v.x; ef_s[pl][1] = v.y; ef_s[pl][2] = v.z; ef_s[pl][3] = v.w;
        } else {
            ef_s[pl][4] = v.x; eh_s[pl] = f2i(v.y); et_s[pl] = f2i(v.z);
        }
    }
    __syncthreads();     // the only barrier

    const int mt   = t >> 6;        // wave id == m-tile
    const int l    = t & 63;        // lane
    const int qt   = l & 3;         // producer: dim-chunk quarter
    const int per  = l >> 2;        // producer: edge row 0..15
    const int row0 = (l >> 4) * 4;  // consumer: accumulator row base
    const int colb = l & 15;        // consumer: column within n-tile
    const int src  = 4 * colb + (l >> 4);   // shfl source for A-frag chunks
    const int bsrc = (l & 48);      // row-group base for ea broadcasts

    int tn[4], hnn[4];
    #pragma unroll
    for (int r = 0; r < 4; ++r) { tn[r] = et_s[mt*16 + row0 + r]; hnn[r] = eh_s[mt*16 + row0 + r]; }

    float efr[FE];
    #pragma unroll
    for (int f = 0; f < FE; ++f) efr[f] = ef_s[mt*16 + per][f];

    auto first_layer = [&](int m, uint4 pk[4]) {
        const float4* w1v = (const float4*)&pw1[m][0];
        const float4* b1v = (const float4*)&pb1[m][0];
        const float4* gv  = (const float4*)&pg[m][0];
        const float4* bev = (const float4*)&pbe[m][0];
        float4 hv[4][2];
        float s1 = 0.f, s2 = 0.f;
        #pragma unroll
        for (int s = 0; s < 4; ++s) {
            #pragma unroll
            for (int hc = 0; hc < 2; ++hc) {
                const int idx = s * 8 + qt * 2 + hc;
                float4 a = b1v[idx];
                #pragma unroll
                for (int f = 0; f < FE; ++f) {
                    const float sc = efr[f];
                    const float4 w = w1v[f * 32 + idx];
                    a.x = fmaf(sc, w.x, a.x); a.y = fmaf(sc, w.y, a.y);
                    a.z = fmaf(sc, w.z, a.z); a.w = fmaf(sc, w.w, a.w);
                }
                a.x = fmaxf(a.x, 0.f); a.y = fmaxf(a.y, 0.f);
                a.z = fmaxf(a.z, 0.f); a.w = fmaxf(a.w, 0.f);
                hv[s][hc] = a;
                s1 += a.x + a.y + a.z + a.w;
                s2 += a.x*a.x + a.y*a.y + a.z*a.z + a.w*a.w;
            }
        }
        s1 += __shfl_xor(s1, 1); s1 += __shfl_xor(s1, 2);
        s2 += __shfl_xor(s2, 1); s2 += __shfl_xor(s2, 2);
        const float mu = s1 * (1.f / 128.f);
        const float rs = rsqrtf(s2 * (1.f / 128.f) - mu * mu + EPS_LN);
        #pragma unroll
        for (int s = 0; s < 4; ++s) {
            const int idx = s * 8 + qt * 2;
            const float4 x0 = hv[s][0], x1 = hv[s][1];
            const float4 g0 = gv[idx], g1 = gv[idx + 1];
            const float4 b0 = bev[idx], b1 = bev[idx + 1];
            Pk8 p8;
            p8.u[0] = f2bf(fmaf((x0.x - mu) * rs, g0.x, b0.x));
            p8.u[1] = f2bf(fmaf((x0.y - mu) * rs, g0.y, b0.y));
            p8.u[2] = f2bf(fmaf((x0.z - mu) * rs, g0.z, b0.z));
            p8.u[3] = f2bf(fmaf((x0.w - mu) * rs, g0.w, b0.w));
            p8.u[4] = f2bf(fmaf((x1.x - mu) * rs, g1.x, b1.x));
            p8.u[5] = f2bf(fmaf((x1.y - mu) * rs, g1.y, b1.y));
            p8.u[6] = f2bf(fmaf((x1.z - mu) * rs, g1.z, b1.z));
            p8.u[7] = f2bf(fmaf((x1.w - mu) * rs, g1.w, b1.w));
            pk[s] = p8.v;
        }
    };

    auto gather_afr = [&](const uint4 pk[4], bf16x8 afr[4]) {
        #pragma unroll
        for (int s = 0; s < 4; ++s) {
            uint4 w;
            w.x = (unsigned)__shfl((int)pk[s].x, src);
            w.y = (unsigned)__shfl((int)pk[s].y, src);
            w.z = (unsigned)__shfl((int)pk[s].z, src);
            w.w = (unsigned)__shfl((int)pk[s].w, src);
            afr[s] = __builtin_bit_cast(bf16x8, w);
        }
    };

    uint4 pk[4];
    bf16x8 afr[4];

    // ================= MLP 0: ea (attention bias, cols padded 8->16) ========
    float eaacc[4];
    first_layer(0, pk);
    gather_afr(pk, afr);
    {
        f32x4 acc = {0.f, 0.f, 0.f, 0.f};
        #pragma unroll
        for (int s = 0; s < 4; ++s) {
            const bf16x8 bfr = *(const bf16x8*)(easw + (size_t)(s * 64 + l) * 8);
            acc = __builtin_amdgcn_mfma_f32_16x16x32_bf16(afr[s], bfr, acc, 0, 0, 0);
        }
        #pragma unroll
        for (int r = 0; r < 4; ++r) eaacc[r] = acc[r];   // raw; bias added later
    }

    // ================= MLP 1: ek -> scores -> exp -> ex_ws ==================
    first_layer(1, pk);
    gather_afr(pk, afr);
    #pragma unroll
    for (int nt = 0; nt < NHEAD; ++nt) {
        f32x4 acc = {0.f, 0.f, 0.f, 0.f};
        #pragma unroll
        for (int s = 0; s < 4; ++s) {
            const bf16x8 bfr = *(const bf16x8*)(eksw + (size_t)((nt * 4 + s) * 64 + l) * 8);
            acc = __builtin_amdgcn_mfma_f32_16x16x32_bf16(afr[s], bfr, acc, 0, 0, 0);
        }
        const int col = nt * 16 + colb;
        const float b2 = pb2k[col];
        const float ba = pb2a[nt];
        float pr[4];
        #pragma unroll
        for (int r = 0; r < 4; ++r)
            pr[r] = (acc[r] + b2 + bf2f(k16[(size_t)tn[r] * D + col]))
                    * bf2f(q16[(size_t)hnn[r] * D + col]);
        #pragma unroll
        for (int m = 1; m < 16; m <<= 1) {
            #pragma unroll
            for (int r = 0; r < 4; ++r) pr[r] += __shfl_xor(pr[r], m);
        }
        #pragma unroll
        for (int r = 0; r < 4; ++r) {
            // segment-max skipped: |score| small, exp cannot overflow.
            const float ea = __shfl(eaacc[r], bsrc | nt);
            const float ex = __expf(pr[r] + ea + ba);
            if (colb == nt)
                ex_ws[(size_t)(e0g + mt*16 + row0 + r) * NHEAD + nt] = ex;
        }
    }

    // ================= MLP 2: ev -> raw vs (bf16) ===========================
    first_layer(2, pk);
    gather_afr(pk, afr);
    #pragma unroll
    for (int nt = 0; nt < NHEAD; ++nt) {
        f32x4 acc = {0.f, 0.f, 0.f, 0.f};
        #pragma unroll
        for (int s = 0; s < 4; ++s) {
            const bf16x8 bfr = *(const bf16x8*)(evsw + (size_t)((nt * 4 + s) * 64 + l) * 8);
            acc = __builtin_amdgcn_mfma_f32_16x16x32_bf16(afr[s], bfr, acc, 0, 0, 0);
        }
        const int col = nt * 16 + colb;
        const float b2 = pb2v[col];
        #pragma unroll
        for (int r = 0; r < 4; ++r) {
            const float vs = acc[r] + b2 + bf2f(v16[(size_t)tn[r] * D + col]);
            vs_ws[(size_t)(e0g + mt*16 + row0 + r) * D + col] = f2bf(vs);
        }
    }
}

// ---------------------------------------------------------------------------
// agg_out: 512 threads, 16 nodes per block, 4 row-groups (4 nodes each).
// Phase 1: stream each node's contiguous sorted segment of (ex, vs) -> LDS y.
// Phase 2: project y @ W + b (each row-group does 4 output rows).
// Plain bounds: no waves/EU contract (R10's (512,4) = only 2 blocks/CU cap).
// ---------------------------------------------------------------------------
__global__ __launch_bounds__(512) void agg_out(
    const int* __restrict__ base,
    const float* __restrict__ ex_ws, const ushort_t* __restrict__ vs_ws,
    const float* __restrict__ W, const float* __restrict__ bias,
    float* __restrict__ out)
{
    __shared__ float xs[D][20];
    const int t  = threadIdx.x;
    const int rg = t >> 7;          // 0..3: node/row group
    const int j  = t & 127;
    const int h  = j >> 4;
    const int n0 = blockIdx.x * 16;

    // ---- phase 1: per-node segmented reduction (contiguous, no indices) ----
    #pragma unroll
    for (int ni = 0; ni < 4; ++ni) {
        const int n  = n0 + rg * 4 + ni;
        const int s0 = base[n], s1 = base[n + 1];
        float acc = 0.f, den = 0.f;
        int p = s0;
        for (; p + 4 <= s1; p += 4) {
            float ex4[4], vs4[4];
            #pragma unroll
            for (int r = 0; r < 4; ++r) {
                ex4[r] = ex_ws[(size_t)(p + r) * NHEAD + h];
                vs4[r] = bf2f(vs_ws[(size_t)(p + r) * D + j]);
            }
            #pragma unroll
            for (int r = 0; r < 4; ++r) {
                den += ex4[r];
                acc = fmaf(ex4[r], vs4[r], acc);
            }
        }
        for (; p < s1; ++p) {
            const float ex = ex_ws[(size_t)p * NHEAD + h];
            den += ex;
            acc = fmaf(ex, bf2f(vs_ws[(size_t)p * D + j]), acc);
        }
        xs[j][rg * 4 + ni] = acc / (den + EPS_SM);
    }
    __syncthreads();

    // ---- phase 2: out projection; row-group rg does rows rg*4..rg*4+4 ------
    float acc[4];
    const float b = bias[j];
    #pragma unroll
    for (int r = 0; r < 4; ++r) acc[r] = b;
    #pragma unroll 4
    for (int i = 0; i < D; ++i) {
        const float w = W[i * D + j];
        const float4 y4 = *(const float4*)&xs[i][rg * 4];
        acc[0] = fmaf(y4.x, w, acc[0]); acc[1] = fmaf(y4.y, w, acc[1]);
        acc[2] = fmaf(y4.z, w, acc[2]); acc[3] = fmaf(y4.w, w, acc[3]);
    }
    #pragma unroll
    for (int r = 0; r < 4; ++r)
        out[(size_t)(n0 + rg * 4 + r) * D + j] = acc[r];
}

// ---------------------------------------------------------------------------
extern "C" void kernel_launch(void* const* d_in, const int* in_sizes, int n_in,
                              void* d_out, int out_size, void* d_ws, size_t ws_size,
                              hipStream_t stream)
{
    const float* key        = (const float*)d_in[0];
    const float* value      = (const float*)d_in[1];
    const float* query      = (const float*)d_in[2];
    const float* edge_feats = (const float*)d_in[3];
    const int*   bidx       = (const int*)d_in[5];
    const int*   hidx       = (const int*)d_in[6];
    const int*   tidx       = (const int*)d_in[7];
    const float* key_w   = (const float*)d_in[8];  const float* key_b   = (const float*)d_in[9];
    const float* query_w = (const float*)d_in[10]; const float* query_b = (const float*)d_in[11];
    const float* value_w = (const float*)d_in[12]; const float* value_b = (const float*)d_in[13];
    const float* proj_w  = (const float*)d_in[14]; const float* proj_b  = (const float*)d_in[15];

    const int N = in_sizes[0] / D;   // 16384 nodes
    const int E = in_sizes[5];       // 262144 edges

    char* ws = (char*)d_ws;
    ushort_t* k16   = (ushort_t*)ws; ws += (size_t)N * D * 2;
    ushort_t* q16   = (ushort_t*)ws; ws += (size_t)N * D * 2;
    ushort_t* v16   = (ushort_t*)ws; ws += (size_t)N * D * 2;
    float* ex_ws    = (float*)ws;    ws += (size_t)E * NHEAD * 4;
    ushort_t* vs_ws = (ushort_t*)ws; ws += (size_t)E * D * 2;
    float* rec      = (float*)ws;    ws += (size_t)E * 8 * 4;
    ushort_t* eksw  = (ushort_t*)ws; ws += (size_t)2048 * 8 * 2;
    ushort_t* evsw  = (ushort_t*)ws; ws += (size_t)2048 * 8 * 2;
    ushort_t* easw  = (ushort_t*)ws; ws += (size_t)256 * 8 * 2;
    int* base = (int*)ws;  ws += (size_t)(N + 1) * 4;
    int* cnt  = (int*)ws;  ws += (size_t)N * 4;

    const int nqb   = N / 32;             // qkv blocks per matrix (512)
    const int nhist = (E + 255) / 256;    // 1024
    const int ngrid = 3 * nqb + 17 + nhist;

    hipMemsetAsync(cnt, 0, (size_t)N * 4, stream);

    setup_kernel<<<ngrid, 256, 0, stream>>>(
        key, value, query,
        key_w, key_b, value_w, value_b, query_w, query_b,
        k16, v16, q16,
        (const float*)d_in[26], (const float*)d_in[32], (const float*)d_in[20],
        eksw, evsw, easw,
        bidx, hidx, cnt, nqb, E);

    scan16k<<<1, 1024, 0, stream>>>(cnt, base);

    scatter_rec<<<(E + 255) / 256, 256, 0, stream>>>(
        bidx, hidx, tidx, edge_feats, base, cnt, rec, E);

    edge_kernel<<<E / EPB, 256, 0, stream>>>(
        rec,
        (const float*)d_in[16], (const float*)d_in[17], (const float*)d_in[18],
        (const float*)d_in[19], (const float*)d_in[21],
        (const float*)d_in[22], (const float*)d_in[23], (const float*)d_in[24],
        (const float*)d_in[25], (const float*)d_in[27],
        (const float*)d_in[28], (const float*)d_in[29], (const float*)d_in[30],
        (const float*)d_in[31], (const float*)d_in[33],
        easw, eksw, evsw,
        k16, q16, v16,
        ex_ws, vs_ws);

    agg_out<<<N / 16, 512, 0, stream>>>(base, ex_ws, vs_ws, proj_w, proj_b, (float*)d_out);
}

// Round 12
// 293.525 us; speedup vs baseline: 1.8272x; 1.0608x over previous
//
#include <hip/hip_runtime.h>
#include <hip/hip_bf16.h>

#define D      128
#define NHEAD  8
#define FE     5
#define LSEQ   4096
#define EPB    64          // edges per block in edge_kernel
#define NNODE  16384
#define EPS_LN 1e-5f
#define EPS_SM 1e-16f

typedef unsigned short ushort_t;
typedef __bf16 bf16x8 __attribute__((ext_vector_type(8)));
typedef float  f32x4  __attribute__((ext_vector_type(4)));

__device__ __forceinline__ ushort_t f2bf(float x) {
    __hip_bfloat16 b = __float2bfloat16(x);
    return __builtin_bit_cast(unsigned short, b);
}
__device__ __forceinline__ float bf2f(ushort_t u) {
    __hip_bfloat16 b = __builtin_bit_cast(__hip_bfloat16, u);
    return __bfloat162float(b);
}
__device__ __forceinline__ float i2f(int x)  { return __builtin_bit_cast(float, x); }
__device__ __forceinline__ int   f2i(float x){ return __builtin_bit_cast(int, x); }

union Pk8 { ushort_t u[8]; uint4 v; };

// ---------------------------------------------------------------------------
// pre_kernel:
//   blocks [0,41)    : swizzle 6 weight matrices into bf16 MFMA B-frag layout
//                      (ek_w2, ev_w2, ea_w2, key_w, query_w, value_w)
//   blocks [41,+1024): head histogram (cnt pre-zeroed by memset)
// Swizzle must precede mid_kernel's MFMA-qkv (separate dispatch = no fence).
// ---------------------------------------------------------------------------
__global__ __launch_bounds__(256) void pre_kernel(
    const float* __restrict__ ekw2, const float* __restrict__ evw2,
    const float* __restrict__ eaw2,
    const float* __restrict__ kw, const float* __restrict__ qw,
    const float* __restrict__ vw,
    ushort_t* __restrict__ eksw, ushort_t* __restrict__ evsw, ushort_t* __restrict__ easw,
    ushort_t* __restrict__ kwsw, ushort_t* __restrict__ qwsw, ushort_t* __restrict__ vwsw,
    const int* __restrict__ bidx, const int* __restrict__ hidx,
    int* __restrict__ cnt, int E)
{
    const int t = threadIdx.x;
    if (blockIdx.x < 41) {
        const int g = blockIdx.x * 256 + t;
        const float* src; ushort_t* dst; int frag, ncols = 128, nvalid = 128;
        if (g < 2048)       { src = ekw2; dst = eksw; frag = g; }
        else if (g < 4096)  { src = evw2; dst = evsw; frag = g - 2048; }
        else if (g < 4352)  { src = eaw2; dst = easw; frag = g - 4096; ncols = 8; nvalid = 8; }
        else if (g < 6400)  { src = kw;   dst = kwsw; frag = g - 4352; }
        else if (g < 8448)  { src = qw;   dst = qwsw; frag = g - 6400; }
        else if (g < 10496) { src = vw;   dst = vwsw; frag = g - 8448; }
        else return;
        const int s = (frag >> 6) & 3;
        const int l = frag & 63;
        const int n = ((frag >> 8) << 4) + (l & 15);
        Pk8 pk;
        #pragma unroll
        for (int j = 0; j < 8; ++j) {
            const int k = s * 32 + (l >> 4) * 8 + j;
            const float v = (n < nvalid) ? src[k * ncols + n] : 0.f;
            pk.u[j] = f2bf(v);
        }
        *(uint4*)(dst + (size_t)frag * 8) = pk.v;
        return;
    }
    // ---------------- histogram ------------------------------------------
    const int e = (blockIdx.x - 41) * 256 + t;
    if (e < E) atomicAdd(&cnt[bidx[e] * LSEQ + hidx[e]], 1);
}

// ---------------------------------------------------------------------------
// Exclusive scan of the 16384-bin histogram (single block, ~5 µs).
// ---------------------------------------------------------------------------
__global__ __launch_bounds__(1024) void scan16k(
    const int* __restrict__ cnt, int* __restrict__ base)
{
    __shared__ int part[1024];
    const int t = threadIdx.x;
    int v[16], ex[16], s = 0;
    #pragma unroll
    for (int i = 0; i < 16; ++i) v[i] = cnt[t * 16 + i];
    #pragma unroll
    for (int i = 0; i < 16; ++i) { ex[i] = s; s += v[i]; }
    part[t] = s;
    __syncthreads();
    for (int off = 1; off < 1024; off <<= 1) {
        const int x = (t >= off) ? part[t - off] : 0;
        __syncthreads();
        part[t] += x;
        __syncthreads();
    }
    const int boff = (t > 0) ? part[t - 1] : 0;
    #pragma unroll
    for (int i = 0; i < 16; ++i) base[t * 16 + i] = boff + ex[i];
    if (t == 1023) base[NNODE] = boff + s;
}

// ---------------------------------------------------------------------------
// mid_kernel: two independent jobs overlapped in one dispatch:
//   blocks [0, 3*nqm)  : MFMA qkv GEMMs, 64 rows/block, bf16 out.
//                        A-frags straight from global X (no LDS), B-frags from
//                        pre-swizzled weights (same layout as edge 2nd layer).
//   blocks [3*nqm, +)  : scatter_rec — sorted slot p per edge, packed 32 B
//                        record rec[p] = {ef[5], head, tail, pad}.
// ---------------------------------------------------------------------------
__global__ __launch_bounds__(256) void mid_kernel(
    const float* __restrict__ key, const float* __restrict__ value,
    const float* __restrict__ query,
    const float* __restrict__ key_b, const float* __restrict__ value_b,
    const float* __restrict__ query_b,
    const ushort_t* __restrict__ kwsw, const ushort_t* __restrict__ vwsw,
    const ushort_t* __restrict__ qwsw,
    ushort_t* __restrict__ k16, ushort_t* __restrict__ v16, ushort_t* __restrict__ q16,
    const int* __restrict__ bidx, const int* __restrict__ hidx, const int* __restrict__ tidx,
    const float* __restrict__ edge_feats,
    const int* __restrict__ base, int* __restrict__ cnt, float* __restrict__ rec,
    int nqm, int E)
{
    const int t  = threadIdx.x;
    const int nq = 3 * nqm;
    if ((int)blockIdx.x < nq) {
        const int which = blockIdx.x / nqm;
        const int blk   = blockIdx.x % nqm;
        const float* X     = (which == 0) ? key   : (which == 1) ? value   : query;
        const float* bias  = (which == 0) ? key_b : (which == 1) ? value_b : query_b;
        const ushort_t* Ww = (which == 0) ? kwsw  : (which == 1) ? vwsw    : qwsw;
        ushort_t* Y        = (which == 0) ? k16   : (which == 1) ? v16     : q16;

        const int mt    = t >> 6;
        const int l     = t & 63;
        const int rbase = blk * 64 + mt * 16;
        const int colb  = l & 15;
        const int row0  = (l >> 4) * 4;
        const int arow  = rbase + colb;        // A row for this lane (m = l&15)
        const int koff  = (l >> 4) * 8;        // k-offset within 32-chunk

        bf16x8 afr[4];
        #pragma unroll
        for (int s = 0; s < 4; ++s) {
            const float4 x0 = *(const float4*)&X[(size_t)arow * D + s * 32 + koff];
            const float4 x1 = *(const float4*)&X[(size_t)arow * D + s * 32 + koff + 4];
            Pk8 p8;
            p8.u[0] = f2bf(x0.x); p8.u[1] = f2bf(x0.y);
            p8.u[2] = f2bf(x0.z); p8.u[3] = f2bf(x0.w);
            p8.u[4] = f2bf(x1.x); p8.u[5] = f2bf(x1.y);
            p8.u[6] = f2bf(x1.z); p8.u[7] = f2bf(x1.w);
            afr[s] = __builtin_bit_cast(bf16x8, p8.v);
        }
        #pragma unroll
        for (int nt = 0; nt < 8; ++nt) {
            f32x4 acc = {0.f, 0.f, 0.f, 0.f};
            #pragma unroll
            for (int s = 0; s < 4; ++s) {
                const bf16x8 bfr = *(const bf16x8*)(Ww + (size_t)((nt * 4 + s) * 64 + l) * 8);
                acc = __builtin_amdgcn_mfma_f32_16x16x32_bf16(afr[s], bfr, acc, 0, 0, 0);
            }
            const int col = nt * 16 + colb;
            const float b = bias[col];
            #pragma unroll
            for (int r = 0; r < 4; ++r)
                Y[(size_t)(rbase + row0 + r) * D + col] = f2bf(acc[r] + b);
        }
        return;
    }

    // ---------------- scatter_rec ----------------------------------------
    const int e = (blockIdx.x - nq) * 256 + t;
    if (e >= E) return;
    const int bb = bidx[e];
    const int nh = bb * LSEQ + hidx[e];
    const int nt = bb * LSEQ + tidx[e];
    const int slot = atomicSub(&cnt[nh], 1) - 1;
    const int p = base[nh] + slot;
    float ef[FE];
    #pragma unroll
    for (int f = 0; f < FE; ++f) ef[f] = edge_feats[(size_t)e * FE + f];
    *(float4*)&rec[(size_t)p * 8]     = float4{ef[0], ef[1], ef[2], ef[3]};
    *(float4*)&rec[(size_t)p * 8 + 4] = float4{ef[4], i2f(nh), i2f(nt), 0.f};
}

// ---------------------------------------------------------------------------
// Fused edge kernel — barrier-free wave-local pipeline over SORTED positions.
// __launch_bounds__(256,4): the ONLY no-spill config. R9 (256,8) -> VGPR 32,
// 1.4 GB scratch; R10 (256,6) -> VGPR 40, 0.85 GB scratch. Natural unified
// VGPR+AGPR footprint is ~128+/wave — do not raise the waves/EU contract.
// ---------------------------------------------------------------------------
__global__ __launch_bounds__(256, 4) void edge_kernel(
    const float* __restrict__ rec,
    const float* __restrict__ ea_w1, const float* __restrict__ ea_b1,
    const float* __restrict__ ea_g,  const float* __restrict__ ea_be, const float* __restrict__ ea_b2,
    const float* __restrict__ ek_w1, const float* __restrict__ ek_b1,
    const float* __restrict__ ek_g,  const float* __restrict__ ek_be, const float* __restrict__ ek_b2,
    const float* __restrict__ ev_w1, const float* __restrict__ ev_b1,
    const float* __restrict__ ev_g,  const float* __restrict__ ev_be, const float* __restrict__ ev_b2,
    const ushort_t* __restrict__ easw, const ushort_t* __restrict__ eksw, const ushort_t* __restrict__ evsw,
    const ushort_t* __restrict__ k16, const ushort_t* __restrict__ q16, const ushort_t* __restrict__ v16,
    float* __restrict__ ex_ws, ushort_t* __restrict__ vs_ws)
{
    __shared__ float pw1[3][FE * D];
    __shared__ float pb1[3][D], pg[3][D], pbe[3][D];
    __shared__ float pb2k[D], pb2v[D], pb2a[NHEAD];
    __shared__ float ef_s[EPB][FE];
    __shared__ int   eh_s[EPB], et_s[EPB];

    const int t   = threadIdx.x;
    const int e0g = blockIdx.x * EPB;   // sorted-position base

    for (int i = t; i < FE * D; i += 256) { pw1[0][i] = ea_w1[i]; pw1[1][i] = ek_w1[i]; pw1[2][i] = ev_w1[i]; }
    if (t < D) {
        pb1[0][t] = ea_b1[t]; pb1[1][t] = ek_b1[t]; pb1[2][t] = ev_b1[t];
        pg [0][t] = ea_g [t]; pg [1][t] = ek_g [t]; pg [2][t] = ev_g [t];
        pbe[0][t] = ea_be[t]; pbe[1][t] = ek_be[t]; pbe[2][t] = ev_be[t];
        pb2k[t] = ek_b2[t];   pb2v[t] = ev_b2[t];
        if (t < NHEAD) pb2a[t] = ea_b2[t];
    }
    if (t < 128) {
        const int pl = t >> 1, half = t & 1;
        const float4 v = *(const float4*)&rec[((size_t)e0g + pl) * 8 + half * 4];
        if (half == 0) {
            ef_s[pl][0] = v.x; ef_s[pl][1] = v.y; ef_s[pl][2] = v.z; ef_s[pl][3] = v.w;
        } else {
            ef_s[pl][4] = v.x; eh_s[pl] = f2i(v.y); et_s[pl] = f2i(v.z);
        }
    }
    __syncthreads();     // the only barrier

    const int mt   = t >> 6;        // wave id == m-tile
    const int l    = t & 63;        // lane
    const int qt   = l & 3;         // producer: dim-chunk quarter
    const int per  = l >> 2;        // producer: edge row 0..15
    const int row0 = (l >> 4) * 4;  // consumer: accumulator row base
    const int colb = l & 15;        // consumer: column within n-tile
    const int src  = 4 * colb + (l >> 4);   // shfl source for A-frag chunks
    const int bsrc = (l & 48);      // row-group base for ea broadcasts

    int tn[4], hnn[4];
    #pragma unroll
    for (int r = 0; r < 4; ++r) { tn[r] = et_s[mt*16 + row0 + r]; hnn[r] = eh_s[mt*16 + row0 + r]; }

    float efr[FE];
    #pragma unroll
    for (int f = 0; f < FE; ++f) efr[f] = ef_s[mt*16 + per][f];

    auto first_layer = [&](int m, uint4 pk[4]) {
        const float4* w1v = (const float4*)&pw1[m][0];
        const float4* b1v = (const float4*)&pb1[m][0];
        const float4* gv  = (const float4*)&pg[m][0];
        const float4* bev = (const float4*)&pbe[m][0];
        float4 hv[4][2];
        float s1 = 0.f, s2 = 0.f;
        #pragma unroll
        for (int s = 0; s < 4; ++s) {
            #pragma unroll
            for (int hc = 0; hc < 2; ++hc) {
                const int idx = s * 8 + qt * 2 + hc;
                float4 a = b1v[idx];
                #pragma unroll
                for (int f = 0; f < FE; ++f) {
                    const float sc = efr[f];
                    const float4 w = w1v[f * 32 + idx];
                    a.x = fmaf(sc, w.x, a.x); a.y = fmaf(sc, w.y, a.y);
                    a.z = fmaf(sc, w.z, a.z); a.w = fmaf(sc, w.w, a.w);
                }
                a.x = fmaxf(a.x, 0.f); a.y = fmaxf(a.y, 0.f);
                a.z = fmaxf(a.z, 0.f); a.w = fmaxf(a.w, 0.f);
                hv[s][hc] = a;
                s1 += a.x + a.y + a.z + a.w;
                s2 += a.x*a.x + a.y*a.y + a.z*a.z + a.w*a.w;
            }
        }
        s1 += __shfl_xor(s1, 1); s1 += __shfl_xor(s1, 2);
        s2 += __shfl_xor(s2, 1); s2 += __shfl_xor(s2, 2);
        const float mu = s1 * (1.f / 128.f);
        const float rs = rsqrtf(s2 * (1.f / 128.f) - mu * mu + EPS_LN);
        #pragma unroll
        for (int s = 0; s < 4; ++s) {
            const int idx = s * 8 + qt * 2;
            const float4 x0 = hv[s][0], x1 = hv[s][1];
            const float4 g0 = gv[idx], g1 = gv[idx + 1];
            const float4 b0 = bev[idx], b1 = bev[idx + 1];
            Pk8 p8;
            p8.u[0] = f2bf(fmaf((x0.x - mu) * rs, g0.x, b0.x));
            p8.u[1] = f2bf(fmaf((x0.y - mu) * rs, g0.y, b0.y));
            p8.u[2] = f2bf(fmaf((x0.z - mu) * rs, g0.z, b0.z));
            p8.u[3] = f2bf(fmaf((x0.w - mu) * rs, g0.w, b0.w));
            p8.u[4] = f2bf(fmaf((x1.x - mu) * rs, g1.x, b1.x));
            p8.u[5] = f2bf(fmaf((x1.y - mu) * rs, g1.y, b1.y));
            p8.u[6] = f2bf(fmaf((x1.z - mu) * rs, g1.z, b1.z));
            p8.u[7] = f2bf(fmaf((x1.w - mu) * rs, g1.w, b1.w));
            pk[s] = p8.v;
        }
    };

    auto gather_afr = [&](const uint4 pk[4], bf16x8 afr[4]) {
        #pragma unroll
        for (int s = 0; s < 4; ++s) {
            uint4 w;
            w.x = (unsigned)__shfl((int)pk[s].x, src);
            w.y = (unsigned)__shfl((int)pk[s].y, src);
            w.z = (unsigned)__shfl((int)pk[s].z, src);
            w.w = (unsigned)__shfl((int)pk[s].w, src);
            afr[s] = __builtin_bit_cast(bf16x8, w);
        }
    };

    uint4 pk[4];
    bf16x8 afr[4];

    // ================= MLP 0: ea (attention bias, cols padded 8->16) ========
    float eaacc[4];
    first_layer(0, pk);
    gather_afr(pk, afr);
    {
        f32x4 acc = {0.f, 0.f, 0.f, 0.f};
        #pragma unroll
        for (int s = 0; s < 4; ++s) {
            const bf16x8 bfr = *(const bf16x8*)(easw + (size_t)(s * 64 + l) * 8);
            acc = __builtin_amdgcn_mfma_f32_16x16x32_bf16(afr[s], bfr, acc, 0, 0, 0);
        }
        #pragma unroll
        for (int r = 0; r < 4; ++r) eaacc[r] = acc[r];   // raw; bias added later
    }

    // ================= MLP 1: ek -> scores -> exp -> ex_ws ==================
    first_layer(1, pk);
    gather_afr(pk, afr);
    #pragma unroll
    for (int nt = 0; nt < NHEAD; ++nt) {
        f32x4 acc = {0.f, 0.f, 0.f, 0.f};
        #pragma unroll
        for (int s = 0; s < 4; ++s) {
            const bf16x8 bfr = *(const bf16x8*)(eksw + (size_t)((nt * 4 + s) * 64 + l) * 8);
            acc = __builtin_amdgcn_mfma_f32_16x16x32_bf16(afr[s], bfr, acc, 0, 0, 0);
        }
        const int col = nt * 16 + colb;
        const float b2 = pb2k[col];
        const float ba = pb2a[nt];
        float pr[4];
        #pragma unroll
        for (int r = 0; r < 4; ++r)
            pr[r] = (acc[r] + b2 + bf2f(k16[(size_t)tn[r] * D + col]))
                    * bf2f(q16[(size_t)hnn[r] * D + col]);
        #pragma unroll
        for (int m = 1; m < 16; m <<= 1) {
            #pragma unroll
            for (int r = 0; r < 4; ++r) pr[r] += __shfl_xor(pr[r], m);
        }
        #pragma unroll
        for (int r = 0; r < 4; ++r) {
            // segment-max skipped: |score| small, exp cannot overflow.
            const float ea = __shfl(eaacc[r], bsrc | nt);
            const float ex = __expf(pr[r] + ea + ba);
            if (colb == nt)
                ex_ws[(size_t)(e0g + mt*16 + row0 + r) * NHEAD + nt] = ex;
        }
    }

    // ================= MLP 2: ev -> raw vs (bf16) ===========================
    first_layer(2, pk);
    gather_afr(pk, afr);
    #pragma unroll
    for (int nt = 0; nt < NHEAD; ++nt) {
        f32x4 acc = {0.f, 0.f, 0.f, 0.f};
        #pragma unroll
        for (int s = 0; s < 4; ++s) {
            const bf16x8 bfr = *(const bf16x8*)(evsw + (size_t)((nt * 4 + s) * 64 + l) * 8);
            acc = __builtin_amdgcn_mfma_f32_16x16x32_bf16(afr[s], bfr, acc, 0, 0, 0);
        }
        const int col = nt * 16 + colb;
        const float b2 = pb2v[col];
        #pragma unroll
        for (int r = 0; r < 4; ++r) {
            const float vs = acc[r] + b2 + bf2f(v16[(size_t)tn[r] * D + col]);
            vs_ws[(size_t)(e0g + mt*16 + row0 + r) * D + col] = f2bf(vs);
        }
    }
}

// ---------------------------------------------------------------------------
// agg_out: 512 threads, 16 nodes per block, 4 row-groups (4 nodes each).
// Phase 1: stream each node's contiguous sorted segment of (ex, vs) -> LDS y.
// Phase 2: project y @ W + b (each row-group does 4 output rows).
// Plain bounds: no waves/EU contract (R9/R10: never squeeze the allocator).
// ---------------------------------------------------------------------------
__global__ __launch_bounds__(512) void agg_out(
    const int* __restrict__ base,
    const float* __restrict__ ex_ws, const ushort_t* __restrict__ vs_ws,
    const float* __restrict__ W, const float* __restrict__ bias,
    float* __restrict__ out)
{
    __shared__ float xs[D][20];
    const int t  = threadIdx.x;
    const int rg = t >> 7;          // 0..3: node/row group
    const int j  = t & 127;
    const int h  = j >> 4;
    const int n0 = blockIdx.x * 16;

    // ---- phase 1: per-node segmented reduction (contiguous, no indices) ----
    #pragma unroll
    for (int ni = 0; ni < 4; ++ni) {
        const int n  = n0 + rg * 4 + ni;
        const int s0 = base[n], s1 = base[n + 1];
        float acc = 0.f, den = 0.f;
        int p = s0;
        for (; p + 4 <= s1; p += 4) {
            float ex4[4], vs4[4];
            #pragma unroll
            for (int r = 0; r < 4; ++r) {
                ex4[r] = ex_ws[(size_t)(p + r) * NHEAD + h];
                vs4[r] = bf2f(vs_ws[(size_t)(p + r) * D + j]);
            }
            #pragma unroll
            for (int r = 0; r < 4; ++r) {
                den += ex4[r];
                acc = fmaf(ex4[r], vs4[r], acc);
            }
        }
        for (; p < s1; ++p) {
            const float ex = ex_ws[(size_t)p * NHEAD + h];
            den += ex;
            acc = fmaf(ex, bf2f(vs_ws[(size_t)p * D + j]), acc);
        }
        xs[j][rg * 4 + ni] = acc / (den + EPS_SM);
    }
    __syncthreads();

    // ---- phase 2: out projection; row-group rg does rows rg*4..rg*4+4 ------
    float acc[4];
    const float b = bias[j];
    #pragma unroll
    for (int r = 0; r < 4; ++r) acc[r] = b;
    #pragma unroll 4
    for (int i = 0; i < D; ++i) {
        const float w = W[i * D + j];
        const float4 y4 = *(const float4*)&xs[i][rg * 4];
        acc[0] = fmaf(y4.x, w, acc[0]); acc[1] = fmaf(y4.y, w, acc[1]);
        acc[2] = fmaf(y4.z, w, acc[2]); acc[3] = fmaf(y4.w, w, acc[3]);
    }
    #pragma unroll
    for (int r = 0; r < 4; ++r)
        out[(size_t)(n0 + rg * 4 + r) * D + j] = acc[r];
}

// ---------------------------------------------------------------------------
extern "C" void kernel_launch(void* const* d_in, const int* in_sizes, int n_in,
                              void* d_out, int out_size, void* d_ws, size_t ws_size,
                              hipStream_t stream)
{
    const float* key        = (const float*)d_in[0];
    const float* value      = (const float*)d_in[1];
    const float* query      = (const float*)d_in[2];
    const float* edge_feats = (const float*)d_in[3];
    const int*   bidx       = (const int*)d_in[5];
    const int*   hidx       = (const int*)d_in[6];
    const int*   tidx       = (const int*)d_in[7];
    const float* key_w   = (const float*)d_in[8];  const float* key_b   = (const float*)d_in[9];
    const float* query_w = (const float*)d_in[10]; const float* query_b = (const float*)d_in[11];
    const float* value_w = (const float*)d_in[12]; const float* value_b = (const float*)d_in[13];
    const float* proj_w  = (const float*)d_in[14]; const float* proj_b  = (const float*)d_in[15];

    const int N = in_sizes[0] / D;   // 16384 nodes
    const int E = in_sizes[5];       // 262144 edges

    char* ws = (char*)d_ws;
    ushort_t* k16   = (ushort_t*)ws; ws += (size_t)N * D * 2;
    ushort_t* q16   = (ushort_t*)ws; ws += (size_t)N * D * 2;
    ushort_t* v16   = (ushort_t*)ws; ws += (size_t)N * D * 2;
    float* ex_ws    = (float*)ws;    ws += (size_t)E * NHEAD * 4;
    ushort_t* vs_ws = (ushort_t*)ws; ws += (size_t)E * D * 2;
    float* rec      = (float*)ws;    ws += (size_t)E * 8 * 4;
    ushort_t* eksw  = (ushort_t*)ws; ws += (size_t)2048 * 8 * 2;
    ushort_t* evsw  = (ushort_t*)ws; ws += (size_t)2048 * 8 * 2;
    ushort_t* easw  = (ushort_t*)ws; ws += (size_t)256 * 8 * 2;
    ushort_t* kwsw  = (ushort_t*)ws; ws += (size_t)2048 * 8 * 2;
    ushort_t* qwsw  = (ushort_t*)ws; ws += (size_t)2048 * 8 * 2;
    ushort_t* vwsw  = (ushort_t*)ws; ws += (size_t)2048 * 8 * 2;
    int* base = (int*)ws;  ws += (size_t)(N + 1) * 4;
    int* cnt  = (int*)ws;  ws += (size_t)N * 4;

    const int nqm   = N / 64;             // MFMA-qkv blocks per matrix (256)
    const int nhist = (E + 255) / 256;    // 1024

    hipMemsetAsync(cnt, 0, (size_t)N * 4, stream);

    pre_kernel<<<41 + nhist, 256, 0, stream>>>(
        (const float*)d_in[26], (const float*)d_in[32], (const float*)d_in[20],
        key_w, query_w, value_w,
        eksw, evsw, easw, kwsw, qwsw, vwsw,
        bidx, hidx, cnt, E);

    scan16k<<<1, 1024, 0, stream>>>(cnt, base);

    mid_kernel<<<3 * nqm + nhist, 256, 0, stream>>>(
        key, value, query,
        key_b, value_b, query_b,
        kwsw, vwsw, qwsw,
        k16, v16, q16,
        bidx, hidx, tidx, edge_feats,
        base, cnt, rec, nqm, E);

    edge_kernel<<<E / EPB, 256, 0, stream>>>(
        rec,
        (const float*)d_in[16], (const float*)d_in[17], (const float*)d_in[18],
        (const float*)d_in[19], (const float*)d_in[21],
        (const float*)d_in[22], (const float*)d_in[23], (const float*)d_in[24],
        (const float*)d_in[25], (const float*)d_in[27],
        (const float*)d_in[28], (const float*)d_in[29], (const float*)d_in[30],
        (const float*)d_in[31], (const float*)d_in[33],
        easw, eksw, evsw,
        k16, q16, v16,
        ex_ws, vs_ws);

    agg_out<<<N / 16, 512, 0, stream>>>(base, ex_ws, vs_ws, proj_w, proj_b, (float*)d_out);
}